// Round 13
// baseline (875.493 us; speedup 1.0000x reference)
//
#include <hip/hip_runtime.h>
#include <math.h>

#define E_NUM 800000
#define CH 256

typedef __attribute__((ext_vector_type(8))) short short8;
typedef __attribute__((ext_vector_type(4))) float float4v;

__device__ __forceinline__ unsigned f2key(float s) {
  unsigned b = __float_as_uint(s);
  return (b & 0x80000000u) ? ~b : (b | 0x80000000u);  // order-preserving
}

// packed 2x16-bit unsigned max; valid as bf16 max for NON-NEGATIVE values
__device__ __forceinline__ unsigned pkmax_u16(unsigned a, unsigned b) {
  unsigned d;
  asm("v_pk_max_u16 %0, %1, %2" : "=v"(d) : "v"(a), "v"(b));
  return d;
}

// ----------------------------- CSR build ------------------------------------

__global__ __launch_bounds__(256) void k_deg(const int* __restrict__ dst, int n,
                                             int* __restrict__ deg) {
  int e = blockIdx.x * 256 + threadIdx.x;
  if (e < E_NUM) { int d = dst[e]; if (d < n) atomicAdd(&deg[d], 1); }
}

// compacted-list degree (levels 2/3): ne from prev level's row[n]
__global__ __launch_bounds__(256) void k_deg_map(const int* __restrict__ esrc,
                                                 const int* __restrict__ edst,
                                                 const int* __restrict__ ecntPtr,
                                                 const int* __restrict__ mapping,
                                                 int* __restrict__ deg) {
  int e = blockIdx.x * 256 + threadIdx.x;
  if (e >= *ecntPtr) return;
  int ms = mapping[esrc[e]];
  int md = mapping[edst[e]];
  if (ms < 0 || md < 0) return;
  atomicAdd(&deg[md], 1);
}

__global__ __launch_bounds__(256) void k_scan_block(const int* __restrict__ deg, int n,
                                                    int* __restrict__ incl,
                                                    int* __restrict__ bsum) {
  __shared__ int s[256];
  int i = blockIdx.x * 256 + threadIdx.x;
  int v = (i < n) ? deg[i] : 0;
  s[threadIdx.x] = v;
  __syncthreads();
  for (int o = 1; o < 256; o <<= 1) {
    int t = (threadIdx.x >= o) ? s[threadIdx.x - o] : 0;
    __syncthreads();
    s[threadIdx.x] += t;
    __syncthreads();
  }
  if (i < n) incl[i] = s[threadIdx.x];
  if (threadIdx.x == 255) bsum[blockIdx.x] = s[255];
}

__global__ void k_scan_bsum(int* bsum, int nb, int* total_out) {
  if (threadIdx.x == 0 && blockIdx.x == 0) {
    int acc = 0;
    for (int b = 0; b < nb; b++) { int v = bsum[b]; bsum[b] = acc; acc += v; }
    total_out[0] = acc;
  }
}

__global__ __launch_bounds__(256) void k_scan_final(const int* __restrict__ deg,
                                                    const int* __restrict__ incl,
                                                    const int* __restrict__ bsum, int n,
                                                    int* __restrict__ row,
                                                    int* __restrict__ cursor) {
  int i = blockIdx.x * 256 + threadIdx.x;
  if (i < n) {
    int r = incl[i] - deg[i] + bsum[blockIdx.x];
    row[i] = r;
    cursor[i] = r;
  }
}

// full-list fill (levels 0/1); dummy edges (dst==n) dropped; optional dstv out.
// CSR positions are dense -> col/dstv form a COMPACTED edge list of row[n] entries.
__global__ __launch_bounds__(256) void k_fill(const int* __restrict__ src,
                                              const int* __restrict__ dst, int n,
                                              int* __restrict__ cursor,
                                              int* __restrict__ col,
                                              int* __restrict__ dstv) {
  int e = blockIdx.x * 256 + threadIdx.x;
  if (e < E_NUM) {
    int d = dst[e];
    if (d < n) {
      int p = atomicAdd(&cursor[d], 1);
      col[p] = src[e];
      if (dstv) dstv[p] = d;
    }
  }
}

// compacted-list fill (levels 2/3)
__global__ __launch_bounds__(256) void k_fill_map(const int* __restrict__ esrc,
                                                  const int* __restrict__ edst,
                                                  const int* __restrict__ ecntPtr,
                                                  const int* __restrict__ mapping,
                                                  int* __restrict__ cursor,
                                                  int* __restrict__ col,
                                                  int* __restrict__ dstv) {
  int e = blockIdx.x * 256 + threadIdx.x;
  if (e >= *ecntPtr) return;
  int ms = mapping[esrc[e]];
  int md = mapping[edst[e]];
  if (ms < 0 || md < 0) return;
  int p = atomicAdd(&cursor[md], 1);
  col[p] = ms;
  if (dstv) dstv[p] = md;
}

// level-1 relabel: one 800k pass, map-gathers ONCE, fused deg, fire-and-forget
__global__ __launch_bounds__(256) void k_relabel_deg(const int* __restrict__ srcIn,
                                                     const int* __restrict__ dstIn,
                                                     const int* __restrict__ mapping,
                                                     int kNew, int* __restrict__ srcOut,
                                                     int* __restrict__ dstOut,
                                                     int* __restrict__ deg) {
  int e = blockIdx.x * 256 + threadIdx.x;
  if (e >= E_NUM) return;
  int ns = mapping[srcIn[e]];
  int nd = mapping[dstIn[e]];
  if (ns >= 0 && nd >= 0) {
    srcOut[e] = ns;
    dstOut[e] = nd;
    atomicAdd(&deg[nd], 1);
  } else {
    srcOut[e] = 0;
    dstOut[e] = kNew;
  }
}

// ----------------------------- max aggregation -------------------------------

__device__ __forceinline__ float4 fmax4(float4 a, float4 b) {
  return make_float4(fmaxf(a.x, b.x), fmaxf(a.y, b.y), fmaxf(a.z, b.z), fmaxf(a.w, b.w));
}

__global__ __launch_bounds__(256) void k_aggmax32(const float* __restrict__ x,
                                                  const int* __restrict__ row,
                                                  const int* __restrict__ col,
                                                  float* __restrict__ out, int n) {
  int node = blockIdx.x * 8 + threadIdx.x / 32;
  int c = threadIdx.x % 32;
  if (node >= n) return;
  int e0 = row[node], e1 = row[node + 1];
  float m0 = -INFINITY, m1 = -INFINITY, m2 = -INFINITY, m3 = -INFINITY;
  int e = e0;
  for (; e + 4 <= e1; e += 4) {
    int s0 = col[e], s1 = col[e + 1], s2 = col[e + 2], s3 = col[e + 3];
    float v0 = x[(size_t)s0 * 32 + c];
    float v1 = x[(size_t)s1 * 32 + c];
    float v2 = x[(size_t)s2 * 32 + c];
    float v3 = x[(size_t)s3 * 32 + c];
    m0 = fmaxf(m0, v0); m1 = fmaxf(m1, v1); m2 = fmaxf(m2, v2); m3 = fmaxf(m3, v3);
  }
  for (; e < e1; e++) m0 = fmaxf(m0, x[(size_t)col[e] * 32 + c]);
  float m = fmaxf(fmaxf(m0, m1), fmaxf(m2, m3));
  out[(size_t)node * 32 + c] = (e1 > e0) ? m : 0.0f;
}

__global__ __launch_bounds__(256) void k_aggmax4(const float* __restrict__ x,
                                                 const int* __restrict__ row,
                                                 const int* __restrict__ col,
                                                 float* __restrict__ out, int n) {
  int lane = threadIdx.x & 63;
  int node = blockIdx.x * 4 + (threadIdx.x >> 6);
  if (node >= n) return;
  int e0 = row[node], e1 = row[node + 1];
  float4 m0 = make_float4(-INFINITY, -INFINITY, -INFINITY, -INFINITY);
  float4 m1 = m0, m2 = m0, m3 = m0;
  int e = e0;
  for (; e + 4 <= e1; e += 4) {
    int s0 = col[e], s1 = col[e + 1], s2 = col[e + 2], s3 = col[e + 3];
    float4 v0 = *(const float4*)&x[(size_t)s0 * CH + lane * 4];
    float4 v1 = *(const float4*)&x[(size_t)s1 * CH + lane * 4];
    float4 v2 = *(const float4*)&x[(size_t)s2 * CH + lane * 4];
    float4 v3 = *(const float4*)&x[(size_t)s3 * CH + lane * 4];
    m0 = fmax4(m0, v0); m1 = fmax4(m1, v1); m2 = fmax4(m2, v2); m3 = fmax4(m3, v3);
  }
  for (; e < e1; e++)
    m0 = fmax4(m0, *(const float4*)&x[(size_t)col[e] * CH + lane * 4]);
  float4 m = fmax4(fmax4(m0, m1), fmax4(m2, m3));
  if (e1 <= e0) m = make_float4(0.f, 0.f, 0.f, 0.f);
  *(float4*)&out[(size_t)node * CH + lane * 4] = m;
}

__device__ __forceinline__ float b2f(unsigned short s) {
  return __uint_as_float(((unsigned)s) << 16);
}

// bf16 table aggmax via packed u16 max (values are non-negative post-ReLU sums)
__global__ __launch_bounds__(256) void k_aggmax4_b16(const unsigned short* __restrict__ xb,
                                                     const int* __restrict__ row,
                                                     const int* __restrict__ col,
                                                     float* __restrict__ out, int n) {
  int lane = threadIdx.x & 63;
  int node = blockIdx.x * 4 + (threadIdx.x >> 6);
  if (node >= n) return;
  int e0 = row[node], e1 = row[node + 1];
  uint2 m0 = make_uint2(0u, 0u), m1 = m0, m2 = m0, m3 = m0;
  int e = e0;
  for (; e + 4 <= e1; e += 4) {
    int s0 = col[e], s1 = col[e + 1], s2 = col[e + 2], s3 = col[e + 3];
    uint2 v0 = *(const uint2*)&xb[(size_t)s0 * CH + lane * 4];
    uint2 v1 = *(const uint2*)&xb[(size_t)s1 * CH + lane * 4];
    uint2 v2 = *(const uint2*)&xb[(size_t)s2 * CH + lane * 4];
    uint2 v3 = *(const uint2*)&xb[(size_t)s3 * CH + lane * 4];
    m0.x = pkmax_u16(m0.x, v0.x); m0.y = pkmax_u16(m0.y, v0.y);
    m1.x = pkmax_u16(m1.x, v1.x); m1.y = pkmax_u16(m1.y, v1.y);
    m2.x = pkmax_u16(m2.x, v2.x); m2.y = pkmax_u16(m2.y, v2.y);
    m3.x = pkmax_u16(m3.x, v3.x); m3.y = pkmax_u16(m3.y, v3.y);
  }
  for (; e < e1; e++) {
    uint2 v = *(const uint2*)&xb[(size_t)col[e] * CH + lane * 4];
    m0.x = pkmax_u16(m0.x, v.x);
    m0.y = pkmax_u16(m0.y, v.y);
  }
  m0.x = pkmax_u16(pkmax_u16(m0.x, m1.x), pkmax_u16(m2.x, m3.x));
  m0.y = pkmax_u16(pkmax_u16(m0.y, m1.y), pkmax_u16(m2.y, m3.y));
  float4 m;
  m.x = b2f((unsigned short)(m0.x & 0xFFFFu));
  m.y = b2f((unsigned short)(m0.x >> 16));
  m.z = b2f((unsigned short)(m0.y & 0xFFFFu));
  m.w = b2f((unsigned short)(m0.y >> 16));
  *(float4*)&out[(size_t)node * CH + lane * 4] = m;
}

// ----------------------------- weight prep -----------------------------------

__global__ __launch_bounds__(256) void k_wprep(const float* __restrict__ src,
                                               unsigned short* __restrict__ dst, int K,
                                               int nmat) {
  int idx = blockIdx.x * 256 + threadIdx.x;
  int total = nmat * K * 256;
  if (idx >= total) return;
  int n = idx % 256;
  int k = (idx / 256) % K;
  int m = idx / (256 * K);
  float v = src[idx];
  unsigned u = __float_as_uint(v);
  unsigned h = u & 0xFFFF0000u;
  float r = v - __uint_as_float(h);
  unsigned short hs = (unsigned short)(h >> 16);
  unsigned short ls = (unsigned short)(__float_as_uint(r) >> 16);
  int ib = k >> 5, kk = k & 31;
  size_t base = (size_t)m * 2 * K * 256;
  size_t o = ((size_t)ib * 256 + n) * 32 + kk;
  dst[base + o] = hs;
  dst[base + (size_t)K * 256 + o] = ls;
}

__device__ __forceinline__ unsigned short f2b_rn(float f) {
  unsigned u = __float_as_uint(f);
  u += 0x7FFFu + ((u >> 16) & 1u);
  return (unsigned short)(u >> 16);
}

// ----------------------------- MFMA dual GEMM --------------------------------
// Operand-swapped MFMA; B fragments direct from prepped global layout.
// terms==3: full split (scoring path). terms==2: A rounded to bf16 (decoder).
// scatter: out[perm[p]] += v; if outb != null, read old f32 from `out` but
// write the bf16 sum to outb instead (dec1 path; bit-identical to f32+convert).

#define KSTR 40

__global__ __launch_bounds__(256) void k_gemm_mfma(
    const float* __restrict__ A1, const float* __restrict__ A2,
    const unsigned short* __restrict__ W1t, const unsigned short* __restrict__ W2t,
    const float* __restrict__ bias, float* __restrict__ out, int M, int K, int scatter,
    const int* __restrict__ perm, const float* __restrict__ scw,
    float* __restrict__ score, unsigned* __restrict__ hist1, int terms,
    unsigned short* __restrict__ outb) {
  __shared__ unsigned short As_h[64 * KSTR], As_l[64 * KSTR];
  __shared__ float sred[4][64];
  const int t = threadIdx.x;
  const int wave = t >> 6, lane = t & 63;
  const int l15 = lane & 15, qd = lane >> 4;
  const int bm0 = blockIdx.x * 64;
  float4v acc[4][4];
#pragma unroll
  for (int a = 0; a < 4; a++)
#pragma unroll
    for (int b = 0; b < 4; b++) acc[a][b] = (float4v)0.f;
  const int sa_m = t >> 2;
  const int sa_kc = (t & 3) * 8;
  const int rok = (bm0 + sa_m) < M;
  const int nIb = K >> 5;
  for (int ib = 0; ib < 2 * nIb; ib++) {
    const float* A = (ib < nIb) ? A1 : A2;
    const unsigned short* Wt = (ib < nIb) ? W1t : W2t;
    int ib0 = (ib < nIb) ? ib : ib - nIb;
    float va[8];
    {
      const float* ap = &A[(size_t)(bm0 + sa_m) * K + (ib0 << 5) + sa_kc];
      float4 v0 = rok ? *(const float4*)ap : make_float4(0, 0, 0, 0);
      float4 v1 = rok ? *(const float4*)(ap + 4) : make_float4(0, 0, 0, 0);
      va[0] = v0.x; va[1] = v0.y; va[2] = v0.z; va[3] = v0.w;
      va[4] = v1.x; va[5] = v1.y; va[6] = v1.z; va[7] = v1.w;
    }
    short8 bh[4], bl[4];
#pragma unroll
    for (int nt = 0; nt < 4; nt++) {
      size_t rowb = ((size_t)ib0 * 256 + wave * 64 + nt * 16 + l15) * 32 + qd * 8;
      bh[nt] = *(const short8*)&Wt[rowb];
      bl[nt] = *(const short8*)&Wt[(size_t)K * 256 + rowb];
    }
    unsigned hp[4], lp[4];
#pragma unroll
    for (int e = 0; e < 4; e++) {
      unsigned u0 = __float_as_uint(va[2 * e]);
      unsigned u1 = __float_as_uint(va[2 * e + 1]);
      unsigned h0 = u0 & 0xFFFF0000u, h1 = u1 & 0xFFFF0000u;
      float r0 = va[2 * e] - __uint_as_float(h0);
      float r1 = va[2 * e + 1] - __uint_as_float(h1);
      hp[e] = (h0 >> 16) | h1;
      lp[e] = (__float_as_uint(r0) >> 16) | (__float_as_uint(r1) & 0xFFFF0000u);
    }
    __syncthreads();
    *(uint4*)&As_h[sa_m * KSTR + sa_kc] = make_uint4(hp[0], hp[1], hp[2], hp[3]);
    if (terms == 3)
      *(uint4*)&As_l[sa_m * KSTR + sa_kc] = make_uint4(lp[0], lp[1], lp[2], lp[3]);
    __syncthreads();
    short8 ah[4], al[4];
#pragma unroll
    for (int mt = 0; mt < 4; mt++) {
      int r = (mt * 16 + l15) * KSTR + qd * 8;
      ah[mt] = *(const short8*)&As_h[r];
      if (terms == 3) al[mt] = *(const short8*)&As_l[r];
    }
#pragma unroll
    for (int mt = 0; mt < 4; mt++)
#pragma unroll
      for (int nt = 0; nt < 4; nt++) {
        acc[mt][nt] =
            __builtin_amdgcn_mfma_f32_16x16x32_bf16(bh[nt], ah[mt], acc[mt][nt], 0, 0, 0);
        acc[mt][nt] =
            __builtin_amdgcn_mfma_f32_16x16x32_bf16(bl[nt], ah[mt], acc[mt][nt], 0, 0, 0);
        if (terms == 3)
          acc[mt][nt] = __builtin_amdgcn_mfma_f32_16x16x32_bf16(bh[nt], al[mt],
                                                                acc[mt][nt], 0, 0, 0);
      }
  }
  const int col0 = wave * 64;
  if (scw) {
    if (t < 64) { sred[0][t] = 0.f; sred[1][t] = 0.f; sred[2][t] = 0.f; sred[3][t] = 0.f; }
    __syncthreads();
  }
  float bias4[4][4], scw4[4][4];
#pragma unroll
  for (int nt = 0; nt < 4; nt++) {
    int cb = col0 + nt * 16 + qd * 4;
    *(float4*)bias4[nt] = *(const float4*)&bias[cb];
    if (scw) *(float4*)scw4[nt] = *(const float4*)&scw[cb];
  }
#pragma unroll
  for (int mt = 0; mt < 4; mt++) {
    int p = bm0 + mt * 16 + l15;
    float sp = 0.f;
    if (p < M) {
      if (scatter) {
        size_t rb = (size_t)perm[p] * CH + col0 + qd * 4;
#pragma unroll
        for (int nt = 0; nt < 4; nt++) {
          float4 old = *(const float4*)&out[rb + nt * 16];
          float4 v;
          v.x = old.x + fmaxf(acc[mt][nt][0] + bias4[nt][0], 0.f);
          v.y = old.y + fmaxf(acc[mt][nt][1] + bias4[nt][1], 0.f);
          v.z = old.z + fmaxf(acc[mt][nt][2] + bias4[nt][2], 0.f);
          v.w = old.w + fmaxf(acc[mt][nt][3] + bias4[nt][3], 0.f);
          if (outb) {
            ushort4 o;
            o.x = f2b_rn(v.x); o.y = f2b_rn(v.y); o.z = f2b_rn(v.z); o.w = f2b_rn(v.w);
            *(ushort4*)&outb[rb + nt * 16] = o;
          } else {
            *(float4*)&out[rb + nt * 16] = v;
          }
        }
      } else {
        size_t rb = (size_t)p * CH + col0 + qd * 4;
#pragma unroll
        for (int nt = 0; nt < 4; nt++) {
          float4 v;
          v.x = fmaxf(acc[mt][nt][0] + bias4[nt][0], 0.f);
          v.y = fmaxf(acc[mt][nt][1] + bias4[nt][1], 0.f);
          v.z = fmaxf(acc[mt][nt][2] + bias4[nt][2], 0.f);
          v.w = fmaxf(acc[mt][nt][3] + bias4[nt][3], 0.f);
          *(float4*)&out[rb + nt * 16] = v;
          if (scw)
            sp += v.x * scw4[nt][0] + v.y * scw4[nt][1] + v.z * scw4[nt][2] +
                  v.w * scw4[nt][3];
        }
      }
    }
    if (scw) {
      sp += __shfl_xor(sp, 16);
      sp += __shfl_xor(sp, 32);
      if (qd == 0) sred[wave][mt * 16 + l15] = sp;
    }
  }
  if (scw) {
    __syncthreads();
    if (t < 64 && bm0 + t < M) {
      float s = sred[0][t] + sred[1][t] + sred[2][t] + sred[3][t];
      score[bm0 + t] = s;
      atomicAdd(&hist1[f2key(s) >> 16], 1u);
    }
  }
}

// ----------------------------- distributed top-k select ----------------------
// state: [0]=Kth key [1]=kneed ties [2]=cnt_keep [3]=cnt_eq [4]=prefix16 [5]=kneed2

__global__ __launch_bounds__(1024) void k_resolve(const unsigned* __restrict__ hist,
                                                  unsigned* __restrict__ state, int pass,
                                                  int k0) {
  __shared__ unsigned csum[1024];
  int t = threadIdx.x;
  int base = 65535 - 64 * t;
  unsigned s = 0;
  for (int j = 0; j < 64; j++) s += hist[base - j];
  csum[t] = s;
  __syncthreads();
  for (int o = 1; o < 1024; o <<= 1) {
    unsigned v = (t >= o) ? csum[t - o] : 0u;
    __syncthreads();
    csum[t] += v;
    __syncthreads();
  }
  unsigned cumBefore = csum[t] - s;
  unsigned kneed = (pass == 0) ? (unsigned)k0 : state[5];
  if (cumBefore < kneed && kneed <= cumBefore + s) {
    unsigned cum = cumBefore;
    for (int j = 0; j < 64; j++) {
      unsigned c = hist[base - j];
      if (cum + c >= kneed) {
        unsigned bucket = (unsigned)(base - j);
        if (pass == 0) {
          state[4] = bucket;
          state[5] = kneed - cum;
        } else {
          state[0] = (state[4] << 16) | bucket;
          state[1] = kneed - cum;
          state[2] = 0u;
          state[3] = 0u;
        }
        break;
      }
      cum += c;
    }
  }
}

__global__ __launch_bounds__(256) void k_hist2(const float* __restrict__ score, int n,
                                               const unsigned* __restrict__ state,
                                               unsigned* __restrict__ hist2) {
  int i = blockIdx.x * 256 + threadIdx.x;
  if (i >= n) return;
  unsigned u = f2key(score[i]);
  if ((u >> 16) == state[4]) atomicAdd(&hist2[u & 0xFFFFu], 1u);
}

__global__ __launch_bounds__(256) void k_compact(const float* __restrict__ score, int n,
                                                 unsigned* __restrict__ state,
                                                 int* __restrict__ perm,
                                                 int* __restrict__ mapping) {
  int i = blockIdx.x * 256 + threadIdx.x;
  if (i > n) return;
  if (i == n) { mapping[n] = -1; return; }
  unsigned Kth = state[0];
  unsigned kneed = state[1];
  unsigned u = f2key(score[i]);
  int m = -1;
  if (u > Kth) {
    unsigned p = atomicAdd(&state[2], 1u);
    perm[p] = i;
    m = (int)p;
  } else if (u == Kth) {
    unsigned tt = atomicAdd(&state[3], 1u);
    if (tt < kneed) {
      unsigned p = atomicAdd(&state[2], 1u);
      perm[p] = i;
      m = (int)p;
    }
  }
  mapping[i] = m;
}

__global__ __launch_bounds__(256) void k_gather(const float* __restrict__ x,
                                                const int* __restrict__ perm,
                                                const float* __restrict__ score,
                                                const float* __restrict__ pw,
                                                float* __restrict__ out, int k) {
  int lane = threadIdx.x & 63;
  int node = blockIdx.x * 4 + (threadIdx.x >> 6);
  float4 w4 = *(const float4*)&pw[lane * 4];
  float nn = w4.x * w4.x + w4.y * w4.y + w4.z * w4.z + w4.w * w4.w;
#pragma unroll
  for (int o = 32; o > 0; o >>= 1) nn += __shfl_down(nn, o);
  nn = __shfl(nn, 0);
  if (node >= k) return;
  int i = perm[node];
  float tv = tanhf(score[i] / sqrtf(nn));
  float4 v = *(const float4*)&x[(size_t)i * CH + lane * 4];
  v.x *= tv; v.y *= tv; v.z *= tv; v.w *= tv;
  *(float4*)&out[(size_t)node * CH + lane * 4] = v;
}

// ----------------------------- final layer -----------------------------------

__global__ __launch_bounds__(256) void k_cvtb16(const float* __restrict__ x,
                                                unsigned short* __restrict__ xb, int n) {
  int lane = threadIdx.x & 63;
  int node = blockIdx.x * 4 + (threadIdx.x >> 6);
  if (node >= n) return;
  float4 a = *(const float4*)&x[(size_t)node * CH + lane * 4];
  ushort4 o;
  o.x = f2b_rn(a.x); o.y = f2b_rn(a.y); o.z = f2b_rn(a.z); o.w = f2b_rn(a.w);
  *(ushort4*)&xb[(size_t)node * CH + lane * 4] = o;
}

// fused maxagg (packed u16 max) + dual GEMM 256->3 + tanh*0.5
__global__ __launch_bounds__(256) void k_final(const unsigned short* __restrict__ XB,
                                               const int* __restrict__ row,
                                               const int* __restrict__ col,
                                               const float* __restrict__ wl,
                                               const float* __restrict__ wr,
                                               const float* __restrict__ b,
                                               float* __restrict__ out, int n) {
  int lane = threadIdx.x & 63;
  int node = blockIdx.x * 4 + (threadIdx.x >> 6);
  if (node >= n) return;
  int e0 = row[node], e1 = row[node + 1];
  uint2 m0 = make_uint2(0u, 0u), m1 = m0, m2 = m0, m3 = m0;
  int e = e0;
  for (; e + 4 <= e1; e += 4) {
    int s0 = col[e], s1 = col[e + 1], s2 = col[e + 2], s3 = col[e + 3];
    uint2 v0 = *(const uint2*)&XB[(size_t)s0 * CH + lane * 4];
    uint2 v1 = *(const uint2*)&XB[(size_t)s1 * CH + lane * 4];
    uint2 v2 = *(const uint2*)&XB[(size_t)s2 * CH + lane * 4];
    uint2 v3 = *(const uint2*)&XB[(size_t)s3 * CH + lane * 4];
    m0.x = pkmax_u16(m0.x, v0.x); m0.y = pkmax_u16(m0.y, v0.y);
    m1.x = pkmax_u16(m1.x, v1.x); m1.y = pkmax_u16(m1.y, v1.y);
    m2.x = pkmax_u16(m2.x, v2.x); m2.y = pkmax_u16(m2.y, v2.y);
    m3.x = pkmax_u16(m3.x, v3.x); m3.y = pkmax_u16(m3.y, v3.y);
  }
  for (; e < e1; e++) {
    uint2 v = *(const uint2*)&XB[(size_t)col[e] * CH + lane * 4];
    m0.x = pkmax_u16(m0.x, v.x);
    m0.y = pkmax_u16(m0.y, v.y);
  }
  m0.x = pkmax_u16(pkmax_u16(m0.x, m1.x), pkmax_u16(m2.x, m3.x));
  m0.y = pkmax_u16(pkmax_u16(m0.y, m1.y), pkmax_u16(m2.y, m3.y));
  float av[4];
  av[0] = b2f((unsigned short)(m0.x & 0xFFFFu));
  av[1] = b2f((unsigned short)(m0.x >> 16));
  av[2] = b2f((unsigned short)(m0.y & 0xFFFFu));
  av[3] = b2f((unsigned short)(m0.y >> 16));
  ushort4 sv4 = *(const ushort4*)&XB[(size_t)node * CH + lane * 4];
  float wlv[12], wrv[12];
  *(float4*)&wlv[0] = ((const float4*)(wl + 12 * lane))[0];
  *(float4*)&wlv[4] = ((const float4*)(wl + 12 * lane))[1];
  *(float4*)&wlv[8] = ((const float4*)(wl + 12 * lane))[2];
  *(float4*)&wrv[0] = ((const float4*)(wr + 12 * lane))[0];
  *(float4*)&wrv[4] = ((const float4*)(wr + 12 * lane))[1];
  *(float4*)&wrv[8] = ((const float4*)(wr + 12 * lane))[2];
  float sv[4] = {b2f(sv4.x), b2f(sv4.y), b2f(sv4.z), b2f(sv4.w)};
  float p[3] = {0.f, 0.f, 0.f};
#pragma unroll
  for (int q = 0; q < 4; q++)
#pragma unroll
    for (int jj = 0; jj < 3; jj++)
      p[jj] += av[q] * wlv[q * 3 + jj] + sv[q] * wrv[q * 3 + jj];
#pragma unroll
  for (int jj = 0; jj < 3; jj++) {
#pragma unroll
    for (int o = 32; o > 0; o >>= 1) p[jj] += __shfl_down(p[jj], o);
  }
  if (lane == 0) {
#pragma unroll
    for (int jj = 0; jj < 3; jj++)
      out[(size_t)node * 3 + jj] = tanhf(p[jj] + b[jj]) * 0.5f;
  }
}

// ----------------------------- host ------------------------------------------

extern "C" void kernel_launch(void* const* d_in, const int* in_sizes, int n_in,
                              void* d_out, int out_size, void* d_ws, size_t ws_size,
                              hipStream_t stream) {
  (void)in_sizes; (void)n_in; (void)out_size; (void)ws_size;
  const float* xin = (const float*)d_in[0];
  const int* ei = (const int*)d_in[1];
  const int* src0 = ei;
  const int* dst0 = ei + E_NUM;
  const float* w0l = (const float*)d_in[2];
  const float* w0r = (const float*)d_in[3];
  const float* b0 = (const float*)d_in[4];
  const float* dwl = (const float*)d_in[5];
  const float* dwr = (const float*)d_in[6];
  const float* db = (const float*)d_in[7];
  const float* poolw = (const float*)d_in[8];
  const float* uwl = (const float*)d_in[9];
  const float* uwr = (const float*)d_in[10];
  const float* ub = (const float*)d_in[11];
  const float* uwlL = (const float*)d_in[12];
  const float* uwrL = (const float*)d_in[13];
  const float* ubL = (const float*)d_in[14];
  float* out = (float*)d_out;

  char* base = (char*)d_ws;
  size_t off = 0;
  auto alloc = [&](size_t bytes) -> void* {
    void* p = base + off;
    off = (off + bytes + 255) & ~(size_t)255;
    return p;
  };

  const int n0 = 50000, n1 = 25000, n2 = 12500, n3 = 6250;
  float* X0 = (float*)alloc((size_t)n0 * CH * 4);
  float* X1 = (float*)alloc((size_t)n1 * CH * 4);
  float* X2 = (float*)alloc((size_t)n2 * CH * 4);
  float* AGG = (float*)alloc((size_t)n1 * CH * 4);
  float* PD = (float*)alloc((size_t)n1 * CH * 4);
  unsigned short* XB = (unsigned short*)alloc((size_t)n0 * CH * 2);
  unsigned short* X1B = (unsigned short*)alloc((size_t)n1 * CH * 2);
  unsigned short* X2B = (unsigned short*)alloc((size_t)n2 * CH * 2);
  int* eA = (int*)alloc((size_t)2 * E_NUM * 4);
  int* col0 = (int*)alloc((size_t)E_NUM * 4);
  int* col1 = (int*)alloc((size_t)E_NUM * 4);
  int* col2 = (int*)alloc((size_t)E_NUM * 4);
  int* col3 = (int*)alloc((size_t)E_NUM * 4);
  int* dstv1 = (int*)alloc((size_t)E_NUM * 4);
  int* dstv2 = (int*)alloc((size_t)E_NUM * 4);
  int* row0 = (int*)alloc((size_t)(n0 + 1) * 4);
  int* row1 = (int*)alloc((size_t)(n1 + 1) * 4);
  int* row2 = (int*)alloc((size_t)(n2 + 1) * 4);
  int* row3 = (int*)alloc((size_t)(n3 + 1) * 4);
  int* map1 = (int*)alloc((size_t)(n0 + 1) * 4);
  int* map2 = (int*)alloc((size_t)(n1 + 1) * 4);
  int* map3 = (int*)alloc((size_t)(n2 + 1) * 4);
  int* perm1 = (int*)alloc((size_t)n1 * 4);
  int* perm2 = (int*)alloc((size_t)n2 * 4);
  int* perm3 = (int*)alloc((size_t)n3 * 4);
  float* score = (float*)alloc((size_t)n0 * 4);
  int* deg = (int*)alloc((size_t)n0 * 4);
  int* incl = (int*)alloc((size_t)n0 * 4);
  int* cursor = (int*)alloc((size_t)n0 * 4);
  int* bsum = (int*)alloc((size_t)256 * 4);
  unsigned* state = (unsigned*)alloc(1024);
  unsigned* hist = (unsigned*)alloc((size_t)2 * 65536 * 4);  // [hist1 | hist2]
  const size_t WSZ = (size_t)2 * 256 * 256;
  unsigned short* Wt0l = (unsigned short*)alloc((size_t)2 * 32 * 256 * 2);
  unsigned short* Wt0r = (unsigned short*)alloc((size_t)2 * 32 * 256 * 2);
  unsigned short* Wtdl = (unsigned short*)alloc(3 * WSZ * 2);
  unsigned short* Wtdr = (unsigned short*)alloc(3 * WSZ * 2);
  unsigned short* Wtul = (unsigned short*)alloc(2 * WSZ * 2);
  unsigned short* Wtur = (unsigned short*)alloc(2 * WSZ * 2);

  const int EG = (E_NUM + 255) / 256;

  k_wprep<<<(32 * 256 + 255) / 256, 256, 0, stream>>>(w0l, Wt0l, 32, 1);
  k_wprep<<<(32 * 256 + 255) / 256, 256, 0, stream>>>(w0r, Wt0r, 32, 1);
  k_wprep<<<(3 * 256 * 256 + 255) / 256, 256, 0, stream>>>(dwl, Wtdl, 256, 3);
  k_wprep<<<(3 * 256 * 256 + 255) / 256, 256, 0, stream>>>(dwr, Wtdr, 256, 3);
  k_wprep<<<(2 * 256 * 256 + 255) / 256, 256, 0, stream>>>(uwl, Wtul, 256, 2);
  k_wprep<<<(2 * 256 * 256 + 255) / 256, 256, 0, stream>>>(uwr, Wtur, 256, 2);

  auto scanLevel = [&](int n, int* rowp) {
    int nb = (n + 255) / 256;
    k_scan_block<<<nb, 256, 0, stream>>>(deg, n, incl, bsum);
    k_scan_bsum<<<1, 1, 0, stream>>>(bsum, nb, rowp + n);
    k_scan_final<<<nb, 256, 0, stream>>>(deg, incl, bsum, n, rowp, cursor);
  };

  auto poolLevel = [&](const float* X, const float* pw, int n, int k, int* mapping,
                       int* permL, float* Pout) {
    k_resolve<<<1, 1024, 0, stream>>>(hist, state, 0, k);
    k_hist2<<<(n + 255) / 256, 256, 0, stream>>>(score, n, state, hist + 65536);
    k_resolve<<<1, 1024, 0, stream>>>(hist + 65536, state, 1, k);
    k_compact<<<(n + 1 + 255) / 256, 256, 0, stream>>>(score, n, state, permL, mapping);
    k_gather<<<(k + 3) / 4, 256, 0, stream>>>(X, permL, score, pw, Pout, k);
  };

  auto gemm = [&](const float* A1, const float* A2, const unsigned short* W1t,
                  const unsigned short* W2t, const float* bias, float* o, int M, int K,
                  int scatter, const int* prm, const float* scw, float* sc, int terms,
                  unsigned short* ob) {
    if (scw) hipMemsetAsync(hist, 0, (size_t)2 * 65536 * 4, stream);
    k_gemm_mfma<<<(M + 63) / 64, 256, 0, stream>>>(A1, A2, W1t, W2t, bias, o, M, K,
                                                   scatter, prm, scw, sc, hist, terms,
                                                   ob);
  };

  // ---------------- encoder ----------------
  hipMemsetAsync(deg, 0, (size_t)n0 * 4, stream);
  k_deg<<<EG, 256, 0, stream>>>(dst0, n0, deg);
  scanLevel(n0, row0);
  k_fill<<<EG, 256, 0, stream>>>(src0, dst0, n0, cursor, col0, nullptr);
  k_aggmax32<<<(n0 + 7) / 8, 256, 0, stream>>>(xin, row0, col0, AGG, n0);
  gemm(AGG, xin, Wt0l, Wt0r, b0, X0, n0, 32, 0, nullptr, poolw + 0 * CH, score, 3,
       nullptr);

  // pool 1 (50000 -> 25000): relabel once (map-gathers once, fused deg), then
  // fill produces COMPACTED col1/dstv1 (dense CSR positions; E1 = row1[n1]).
  poolLevel(X0, poolw + 0 * CH, n0, n1, map1, perm1, PD);
  hipMemsetAsync(deg, 0, (size_t)n1 * 4, stream);
  k_relabel_deg<<<EG, 256, 0, stream>>>(src0, dst0, map1, n1, eA, eA + E_NUM, deg);
  scanLevel(n1, row1);
  k_fill<<<EG, 256, 0, stream>>>(eA, eA + E_NUM, n1, cursor, col1, dstv1);
  k_aggmax4<<<(n1 + 3) / 4, 256, 0, stream>>>(PD, row1, col1, AGG, n1);
  gemm(AGG, PD, Wtdl + 0 * WSZ, Wtdr + 0 * WSZ, db + 0 * CH, X1, n1, 256, 0, nullptr,
       poolw + 1 * CH, score, 3, nullptr);

  // pool 2 (25000 -> 12500): compacted scan over E1 entries
  poolLevel(X1, poolw + 1 * CH, n1, n2, map2, perm2, PD);
  hipMemsetAsync(deg, 0, (size_t)n2 * 4, stream);
  k_deg_map<<<EG, 256, 0, stream>>>(col1, dstv1, row1 + n1, map2, deg);
  scanLevel(n2, row2);
  k_fill_map<<<EG, 256, 0, stream>>>(col1, dstv1, row1 + n1, map2, cursor, col2, dstv2);
  k_aggmax4<<<(n2 + 3) / 4, 256, 0, stream>>>(PD, row2, col2, AGG, n2);
  gemm(AGG, PD, Wtdl + 1 * WSZ, Wtdr + 1 * WSZ, db + 1 * CH, X2, n2, 256, 0, nullptr,
       poolw + 2 * CH, score, 3, nullptr);

  // pool 3 (12500 -> 6250): compacted scan over E2 entries
  poolLevel(X2, poolw + 2 * CH, n2, n3, map3, perm3, PD);
  hipMemsetAsync(deg, 0, (size_t)n3 * 4, stream);
  k_deg_map<<<EG, 256, 0, stream>>>(col2, dstv2, row2 + n2, map3, deg);
  scanLevel(n3, row3);
  k_fill_map<<<EG, 256, 0, stream>>>(col2, dstv2, row2 + n2, map3, cursor, col3, nullptr);
  k_aggmax4<<<(n3 + 3) / 4, 256, 0, stream>>>(PD, row3, col3, AGG, n3);
  gemm(AGG, PD, Wtdl + 2 * WSZ, Wtdr + 2 * WSZ, db + 2 * CH, X2, n3, 256, 1, perm3,
       nullptr, nullptr, 2, nullptr);

  // ---------------- decoder (bf16 gather tables) ----------------
  k_cvtb16<<<(n2 + 3) / 4, 256, 0, stream>>>(X2, X2B, n2);
  k_aggmax4_b16<<<(n2 + 3) / 4, 256, 0, stream>>>(X2B, row2, col2, AGG, n2);
  gemm(AGG, X2, Wtul + 0 * WSZ, Wtur + 0 * WSZ, ub + 0 * CH, X1, n2, 256, 1, perm2,
       nullptr, nullptr, 2, nullptr);

  k_cvtb16<<<(n1 + 3) / 4, 256, 0, stream>>>(X1, X1B, n1);
  k_aggmax4_b16<<<(n1 + 3) / 4, 256, 0, stream>>>(X1B, row1, col1, AGG, n1);
  // dec1: convert encoder X0 to bf16 first; scatter epilogue reads old f32 X0
  // and writes bf16 sums directly into XB (bit-identical to f32+convert).
  k_cvtb16<<<(n0 + 3) / 4, 256, 0, stream>>>(X0, XB, n0);
  gemm(AGG, X1, Wtul + 1 * WSZ, Wtur + 1 * WSZ, ub + 1 * CH, X0, n1, 256, 1, perm1,
       nullptr, nullptr, 2, XB);

  k_final<<<(n0 + 3) / 4, 256, 0, stream>>>(XB, row0, col0, uwlL, uwrL, ubL, out, n0);
}

// Round 14
// 819.594 us; speedup vs baseline: 1.0682x; 1.0682x over previous
//
#include <hip/hip_runtime.h>
#include <math.h>

#define E_NUM 800000
#define CH 256

typedef __attribute__((ext_vector_type(8))) short short8;
typedef __attribute__((ext_vector_type(4))) float float4v;

__device__ __forceinline__ unsigned f2key(float s) {
  unsigned b = __float_as_uint(s);
  return (b & 0x80000000u) ? ~b : (b | 0x80000000u);  // order-preserving
}

// packed 2x16-bit unsigned max; valid as bf16 max for NON-NEGATIVE values
__device__ __forceinline__ unsigned pkmax_u16(unsigned a, unsigned b) {
  unsigned d;
  asm("v_pk_max_u16 %0, %1, %2" : "=v"(d) : "v"(a), "v"(b));
  return d;
}

// ----------------------------- CSR build ------------------------------------

__global__ __launch_bounds__(256) void k_deg(const int* __restrict__ dst, int n,
                                             int* __restrict__ deg) {
  int e = blockIdx.x * 256 + threadIdx.x;
  if (e < E_NUM) { int d = dst[e]; if (d < n) atomicAdd(&deg[d], 1); }
}

__global__ __launch_bounds__(256) void k_scan_block(const int* __restrict__ deg, int n,
                                                    int* __restrict__ incl,
                                                    int* __restrict__ bsum) {
  __shared__ int s[256];
  int i = blockIdx.x * 256 + threadIdx.x;
  int v = (i < n) ? deg[i] : 0;
  s[threadIdx.x] = v;
  __syncthreads();
  for (int o = 1; o < 256; o <<= 1) {
    int t = (threadIdx.x >= o) ? s[threadIdx.x - o] : 0;
    __syncthreads();
    s[threadIdx.x] += t;
    __syncthreads();
  }
  if (i < n) incl[i] = s[threadIdx.x];
  if (threadIdx.x == 255) bsum[blockIdx.x] = s[255];
}

// fused: each block computes its own bsum prefix (nb <= 196, cheap); last block
// writes row[n]. Removes the serialized 1-thread scan_bsum kernel.
__global__ __launch_bounds__(256) void k_scan_final(const int* __restrict__ deg,
                                                    const int* __restrict__ incl,
                                                    const int* __restrict__ bsum, int n,
                                                    int* __restrict__ row,
                                                    int* __restrict__ cursor) {
  __shared__ int red[256];
  int tid = threadIdx.x;
  int partial = 0;
  for (int b = tid; b < (int)blockIdx.x; b += 256) partial += bsum[b];
  red[tid] = partial;
  __syncthreads();
  for (int o = 128; o > 0; o >>= 1) {
    if (tid < o) red[tid] += red[tid + o];
    __syncthreads();
  }
  int base = red[0];
  int i = blockIdx.x * 256 + tid;
  if (i < n) {
    int r = incl[i] - deg[i] + base;
    row[i] = r;
    cursor[i] = r;
  }
  if (blockIdx.x == gridDim.x - 1 && tid == 0) row[n] = base + bsum[blockIdx.x];
}

// dummy edges have dst == n -> dropped by the d < n guard
__global__ __launch_bounds__(256) void k_fill(const int* __restrict__ src,
                                              const int* __restrict__ dst, int n,
                                              int* __restrict__ cursor,
                                              int* __restrict__ col) {
  int e = blockIdx.x * 256 + threadIdx.x;
  if (e < E_NUM) {
    int d = dst[e];
    if (d < n) { int p = atomicAdd(&cursor[d], 1); col[p] = src[e]; }
  }
}

// relabel, NON-compacting (fire-and-forget; no wave-blocking dependency)
__global__ __launch_bounds__(256) void k_relabel_deg(const int* __restrict__ srcIn,
                                                     const int* __restrict__ dstIn,
                                                     const int* __restrict__ mapping,
                                                     int kNew, int* __restrict__ srcOut,
                                                     int* __restrict__ dstOut,
                                                     int* __restrict__ deg) {
  int e = blockIdx.x * 256 + threadIdx.x;
  if (e >= E_NUM) return;
  int ns = mapping[srcIn[e]];
  int nd = mapping[dstIn[e]];
  if (ns >= 0 && nd >= 0) {
    srcOut[e] = ns;
    dstOut[e] = nd;
    atomicAdd(&deg[nd], 1);
  } else {
    srcOut[e] = 0;
    dstOut[e] = kNew;
  }
}

// ----------------------------- max aggregation -------------------------------

__device__ __forceinline__ float4 fmax4(float4 a, float4 b) {
  return make_float4(fmaxf(a.x, b.x), fmaxf(a.y, b.y), fmaxf(a.z, b.z), fmaxf(a.w, b.w));
}

__global__ __launch_bounds__(256) void k_aggmax32(const float* __restrict__ x,
                                                  const int* __restrict__ row,
                                                  const int* __restrict__ col,
                                                  float* __restrict__ out, int n) {
  int node = blockIdx.x * 8 + threadIdx.x / 32;
  int c = threadIdx.x % 32;
  if (node >= n) return;
  int e0 = row[node], e1 = row[node + 1];
  float m0 = -INFINITY, m1 = -INFINITY, m2 = -INFINITY, m3 = -INFINITY;
  int e = e0;
  for (; e + 4 <= e1; e += 4) {
    int s0 = col[e], s1 = col[e + 1], s2 = col[e + 2], s3 = col[e + 3];
    float v0 = x[(size_t)s0 * 32 + c];
    float v1 = x[(size_t)s1 * 32 + c];
    float v2 = x[(size_t)s2 * 32 + c];
    float v3 = x[(size_t)s3 * 32 + c];
    m0 = fmaxf(m0, v0); m1 = fmaxf(m1, v1); m2 = fmaxf(m2, v2); m3 = fmaxf(m3, v3);
  }
  for (; e < e1; e++) m0 = fmaxf(m0, x[(size_t)col[e] * 32 + c]);
  float m = fmaxf(fmaxf(m0, m1), fmaxf(m2, m3));
  out[(size_t)node * 32 + c] = (e1 > e0) ? m : 0.0f;
}

__global__ __launch_bounds__(256) void k_aggmax4(const float* __restrict__ x,
                                                 const int* __restrict__ row,
                                                 const int* __restrict__ col,
                                                 float* __restrict__ out, int n) {
  int lane = threadIdx.x & 63;
  int node = blockIdx.x * 4 + (threadIdx.x >> 6);
  if (node >= n) return;
  int e0 = row[node], e1 = row[node + 1];
  float4 m0 = make_float4(-INFINITY, -INFINITY, -INFINITY, -INFINITY);
  float4 m1 = m0, m2 = m0, m3 = m0;
  int e = e0;
  for (; e + 4 <= e1; e += 4) {
    int s0 = col[e], s1 = col[e + 1], s2 = col[e + 2], s3 = col[e + 3];
    float4 v0 = *(const float4*)&x[(size_t)s0 * CH + lane * 4];
    float4 v1 = *(const float4*)&x[(size_t)s1 * CH + lane * 4];
    float4 v2 = *(const float4*)&x[(size_t)s2 * CH + lane * 4];
    float4 v3 = *(const float4*)&x[(size_t)s3 * CH + lane * 4];
    m0 = fmax4(m0, v0); m1 = fmax4(m1, v1); m2 = fmax4(m2, v2); m3 = fmax4(m3, v3);
  }
  for (; e < e1; e++)
    m0 = fmax4(m0, *(const float4*)&x[(size_t)col[e] * CH + lane * 4]);
  float4 m = fmax4(fmax4(m0, m1), fmax4(m2, m3));
  if (e1 <= e0) m = make_float4(0.f, 0.f, 0.f, 0.f);
  *(float4*)&out[(size_t)node * CH + lane * 4] = m;
}

__device__ __forceinline__ float b2f(unsigned short s) {
  return __uint_as_float(((unsigned)s) << 16);
}

// bf16 table aggmax via packed u16 max (values are non-negative post-ReLU sums)
__global__ __launch_bounds__(256) void k_aggmax4_b16(const unsigned short* __restrict__ xb,
                                                     const int* __restrict__ row,
                                                     const int* __restrict__ col,
                                                     float* __restrict__ out, int n) {
  int lane = threadIdx.x & 63;
  int node = blockIdx.x * 4 + (threadIdx.x >> 6);
  if (node >= n) return;
  int e0 = row[node], e1 = row[node + 1];
  uint2 m0 = make_uint2(0u, 0u), m1 = m0, m2 = m0, m3 = m0;
  int e = e0;
  for (; e + 4 <= e1; e += 4) {
    int s0 = col[e], s1 = col[e + 1], s2 = col[e + 2], s3 = col[e + 3];
    uint2 v0 = *(const uint2*)&xb[(size_t)s0 * CH + lane * 4];
    uint2 v1 = *(const uint2*)&xb[(size_t)s1 * CH + lane * 4];
    uint2 v2 = *(const uint2*)&xb[(size_t)s2 * CH + lane * 4];
    uint2 v3 = *(const uint2*)&xb[(size_t)s3 * CH + lane * 4];
    m0.x = pkmax_u16(m0.x, v0.x); m0.y = pkmax_u16(m0.y, v0.y);
    m1.x = pkmax_u16(m1.x, v1.x); m1.y = pkmax_u16(m1.y, v1.y);
    m2.x = pkmax_u16(m2.x, v2.x); m2.y = pkmax_u16(m2.y, v2.y);
    m3.x = pkmax_u16(m3.x, v3.x); m3.y = pkmax_u16(m3.y, v3.y);
  }
  for (; e < e1; e++) {
    uint2 v = *(const uint2*)&xb[(size_t)col[e] * CH + lane * 4];
    m0.x = pkmax_u16(m0.x, v.x);
    m0.y = pkmax_u16(m0.y, v.y);
  }
  m0.x = pkmax_u16(pkmax_u16(m0.x, m1.x), pkmax_u16(m2.x, m3.x));
  m0.y = pkmax_u16(pkmax_u16(m0.y, m1.y), pkmax_u16(m2.y, m3.y));
  float4 m;
  m.x = b2f((unsigned short)(m0.x & 0xFFFFu));
  m.y = b2f((unsigned short)(m0.x >> 16));
  m.z = b2f((unsigned short)(m0.y & 0xFFFFu));
  m.w = b2f((unsigned short)(m0.y >> 16));
  *(float4*)&out[(size_t)node * CH + lane * 4] = m;
}

// ----------------------------- weight prep (fused, 1 launch) ------------------
// segments: w0l[8192] w0r[8192] dwl[196608] dwr[196608] uwl[131072] uwr[131072]

__global__ __launch_bounds__(256) void k_wprep_all(
    const float* __restrict__ w0l, const float* __restrict__ w0r,
    const float* __restrict__ dwl, const float* __restrict__ dwr,
    const float* __restrict__ uwl, const float* __restrict__ uwr,
    unsigned short* __restrict__ Wt0l, unsigned short* __restrict__ Wt0r,
    unsigned short* __restrict__ Wtdl, unsigned short* __restrict__ Wtdr,
    unsigned short* __restrict__ Wtul, unsigned short* __restrict__ Wtur) {
  int idx = blockIdx.x * 256 + threadIdx.x;
  const float* src;
  unsigned short* dst;
  int K, rel;
  if (idx < 8192) { src = w0l; dst = Wt0l; K = 32; rel = idx; }
  else if (idx < 16384) { src = w0r; dst = Wt0r; K = 32; rel = idx - 8192; }
  else if (idx < 212992) { src = dwl; dst = Wtdl; K = 256; rel = idx - 16384; }
  else if (idx < 409600) { src = dwr; dst = Wtdr; K = 256; rel = idx - 212992; }
  else if (idx < 540672) { src = uwl; dst = Wtul; K = 256; rel = idx - 409600; }
  else if (idx < 671744) { src = uwr; dst = Wtur; K = 256; rel = idx - 540672; }
  else return;
  int n = rel % 256;
  int k = (rel / 256) % K;
  int m = rel / (256 * K);
  float v = src[rel];
  unsigned u = __float_as_uint(v);
  unsigned h = u & 0xFFFF0000u;
  float r = v - __uint_as_float(h);
  unsigned short hs = (unsigned short)(h >> 16);
  unsigned short ls = (unsigned short)(__float_as_uint(r) >> 16);
  int ib = k >> 5, kk = k & 31;
  size_t base = (size_t)m * 2 * K * 256;
  size_t o = ((size_t)ib * 256 + n) * 32 + kk;
  dst[base + o] = hs;
  dst[base + (size_t)K * 256 + o] = ls;
}

__device__ __forceinline__ unsigned short f2b_rn(float f) {
  unsigned u = __float_as_uint(f);
  u += 0x7FFFu + ((u >> 16) & 1u);
  return (unsigned short)(u >> 16);
}

// ----------------------------- MFMA dual GEMM --------------------------------
// Operand-swapped MFMA; B fragments direct from prepped global layout.
// terms==3: full split (scoring path, selection-exact). terms==2: A rounded to
// bf16 (decoder scatter path, post-selection). scatter+outb: read old f32 from
// `out`, write bf16 sum to outb (dec1; bit-identical to f32-write+convert).

#define KSTR 40

__global__ __launch_bounds__(256) void k_gemm_mfma(
    const float* __restrict__ A1, const float* __restrict__ A2,
    const unsigned short* __restrict__ W1t, const unsigned short* __restrict__ W2t,
    const float* __restrict__ bias, float* __restrict__ out, int M, int K, int scatter,
    const int* __restrict__ perm, const float* __restrict__ scw,
    float* __restrict__ score, unsigned* __restrict__ hist1, int terms,
    unsigned short* __restrict__ outb) {
  __shared__ unsigned short As_h[64 * KSTR], As_l[64 * KSTR];
  __shared__ float sred[4][64];
  const int t = threadIdx.x;
  const int wave = t >> 6, lane = t & 63;
  const int l15 = lane & 15, qd = lane >> 4;
  const int bm0 = blockIdx.x * 64;
  float4v acc[4][4];
#pragma unroll
  for (int a = 0; a < 4; a++)
#pragma unroll
    for (int b = 0; b < 4; b++) acc[a][b] = (float4v)0.f;
  const int sa_m = t >> 2;
  const int sa_kc = (t & 3) * 8;
  const int rok = (bm0 + sa_m) < M;
  const int nIb = K >> 5;
  for (int ib = 0; ib < 2 * nIb; ib++) {
    const float* A = (ib < nIb) ? A1 : A2;
    const unsigned short* Wt = (ib < nIb) ? W1t : W2t;
    int ib0 = (ib < nIb) ? ib : ib - nIb;
    float va[8];
    {
      const float* ap = &A[(size_t)(bm0 + sa_m) * K + (ib0 << 5) + sa_kc];
      float4 v0 = rok ? *(const float4*)ap : make_float4(0, 0, 0, 0);
      float4 v1 = rok ? *(const float4*)(ap + 4) : make_float4(0, 0, 0, 0);
      va[0] = v0.x; va[1] = v0.y; va[2] = v0.z; va[3] = v0.w;
      va[4] = v1.x; va[5] = v1.y; va[6] = v1.z; va[7] = v1.w;
    }
    short8 bh[4], bl[4];
#pragma unroll
    for (int nt = 0; nt < 4; nt++) {
      size_t rowb = ((size_t)ib0 * 256 + wave * 64 + nt * 16 + l15) * 32 + qd * 8;
      bh[nt] = *(const short8*)&Wt[rowb];
      bl[nt] = *(const short8*)&Wt[(size_t)K * 256 + rowb];
    }
    unsigned hp[4], lp[4];
#pragma unroll
    for (int e = 0; e < 4; e++) {
      unsigned u0 = __float_as_uint(va[2 * e]);
      unsigned u1 = __float_as_uint(va[2 * e + 1]);
      unsigned h0 = u0 & 0xFFFF0000u, h1 = u1 & 0xFFFF0000u;
      float r0 = va[2 * e] - __uint_as_float(h0);
      float r1 = va[2 * e + 1] - __uint_as_float(h1);
      hp[e] = (h0 >> 16) | h1;
      lp[e] = (__float_as_uint(r0) >> 16) | (__float_as_uint(r1) & 0xFFFF0000u);
    }
    __syncthreads();
    *(uint4*)&As_h[sa_m * KSTR + sa_kc] = make_uint4(hp[0], hp[1], hp[2], hp[3]);
    if (terms == 3)
      *(uint4*)&As_l[sa_m * KSTR + sa_kc] = make_uint4(lp[0], lp[1], lp[2], lp[3]);
    __syncthreads();
    short8 ah[4], al[4];
#pragma unroll
    for (int mt = 0; mt < 4; mt++) {
      int r = (mt * 16 + l15) * KSTR + qd * 8;
      ah[mt] = *(const short8*)&As_h[r];
      if (terms == 3) al[mt] = *(const short8*)&As_l[r];
    }
#pragma unroll
    for (int mt = 0; mt < 4; mt++)
#pragma unroll
      for (int nt = 0; nt < 4; nt++) {
        acc[mt][nt] =
            __builtin_amdgcn_mfma_f32_16x16x32_bf16(bh[nt], ah[mt], acc[mt][nt], 0, 0, 0);
        acc[mt][nt] =
            __builtin_amdgcn_mfma_f32_16x16x32_bf16(bl[nt], ah[mt], acc[mt][nt], 0, 0, 0);
        if (terms == 3)
          acc[mt][nt] = __builtin_amdgcn_mfma_f32_16x16x32_bf16(bh[nt], al[mt],
                                                                acc[mt][nt], 0, 0, 0);
      }
  }
  const int col0 = wave * 64;
  if (scw) {
    if (t < 64) { sred[0][t] = 0.f; sred[1][t] = 0.f; sred[2][t] = 0.f; sred[3][t] = 0.f; }
    __syncthreads();
  }
  float bias4[4][4], scw4[4][4];
#pragma unroll
  for (int nt = 0; nt < 4; nt++) {
    int cb = col0 + nt * 16 + qd * 4;
    *(float4*)bias4[nt] = *(const float4*)&bias[cb];
    if (scw) *(float4*)scw4[nt] = *(const float4*)&scw[cb];
  }
#pragma unroll
  for (int mt = 0; mt < 4; mt++) {
    int p = bm0 + mt * 16 + l15;
    float sp = 0.f;
    if (p < M) {
      if (scatter) {
        size_t rb = (size_t)perm[p] * CH + col0 + qd * 4;
#pragma unroll
        for (int nt = 0; nt < 4; nt++) {
          float4 old = *(const float4*)&out[rb + nt * 16];
          float4 v;
          v.x = old.x + fmaxf(acc[mt][nt][0] + bias4[nt][0], 0.f);
          v.y = old.y + fmaxf(acc[mt][nt][1] + bias4[nt][1], 0.f);
          v.z = old.z + fmaxf(acc[mt][nt][2] + bias4[nt][2], 0.f);
          v.w = old.w + fmaxf(acc[mt][nt][3] + bias4[nt][3], 0.f);
          if (outb) {
            ushort4 o;
            o.x = f2b_rn(v.x); o.y = f2b_rn(v.y); o.z = f2b_rn(v.z); o.w = f2b_rn(v.w);
            *(ushort4*)&outb[rb + nt * 16] = o;
          } else {
            *(float4*)&out[rb + nt * 16] = v;
          }
        }
      } else {
        size_t rb = (size_t)p * CH + col0 + qd * 4;
#pragma unroll
        for (int nt = 0; nt < 4; nt++) {
          float4 v;
          v.x = fmaxf(acc[mt][nt][0] + bias4[nt][0], 0.f);
          v.y = fmaxf(acc[mt][nt][1] + bias4[nt][1], 0.f);
          v.z = fmaxf(acc[mt][nt][2] + bias4[nt][2], 0.f);
          v.w = fmaxf(acc[mt][nt][3] + bias4[nt][3], 0.f);
          *(float4*)&out[rb + nt * 16] = v;
          if (scw)
            sp += v.x * scw4[nt][0] + v.y * scw4[nt][1] + v.z * scw4[nt][2] +
                  v.w * scw4[nt][3];
        }
      }
    }
    if (scw) {
      sp += __shfl_xor(sp, 16);
      sp += __shfl_xor(sp, 32);
      if (qd == 0) sred[wave][mt * 16 + l15] = sp;
    }
  }
  if (scw) {
    __syncthreads();
    if (t < 64 && bm0 + t < M) {
      float s = sred[0][t] + sred[1][t] + sred[2][t] + sred[3][t];
      score[bm0 + t] = s;
      atomicAdd(&hist1[f2key(s) >> 16], 1u);
    }
  }
}

// ----------------------------- distributed top-k select ----------------------
// state: [0]=Kth key [1]=kneed ties [2]=cnt_keep [3]=cnt_eq [4]=prefix16 [5]=kneed2

__global__ __launch_bounds__(1024) void k_resolve(const unsigned* __restrict__ hist,
                                                  unsigned* __restrict__ state, int pass,
                                                  int k0) {
  __shared__ unsigned csum[1024];
  int t = threadIdx.x;
  int base = 65535 - 64 * t;
  unsigned s = 0;
  for (int j = 0; j < 64; j++) s += hist[base - j];
  csum[t] = s;
  __syncthreads();
  for (int o = 1; o < 1024; o <<= 1) {
    unsigned v = (t >= o) ? csum[t - o] : 0u;
    __syncthreads();
    csum[t] += v;
    __syncthreads();
  }
  unsigned cumBefore = csum[t] - s;
  unsigned kneed = (pass == 0) ? (unsigned)k0 : state[5];
  if (cumBefore < kneed && kneed <= cumBefore + s) {
    unsigned cum = cumBefore;
    for (int j = 0; j < 64; j++) {
      unsigned c = hist[base - j];
      if (cum + c >= kneed) {
        unsigned bucket = (unsigned)(base - j);
        if (pass == 0) {
          state[4] = bucket;
          state[5] = kneed - cum;
        } else {
          state[0] = (state[4] << 16) | bucket;
          state[1] = kneed - cum;
          state[2] = 0u;
          state[3] = 0u;
        }
        break;
      }
      cum += c;
    }
  }
}

__global__ __launch_bounds__(256) void k_hist2(const float* __restrict__ score, int n,
                                               const unsigned* __restrict__ state,
                                               unsigned* __restrict__ hist2) {
  int i = blockIdx.x * 256 + threadIdx.x;
  if (i >= n) return;
  unsigned u = f2key(score[i]);
  if ((u >> 16) == state[4]) atomicAdd(&hist2[u & 0xFFFFu], 1u);
}

__global__ __launch_bounds__(256) void k_compact(const float* __restrict__ score, int n,
                                                 unsigned* __restrict__ state,
                                                 int* __restrict__ perm,
                                                 int* __restrict__ mapping) {
  int i = blockIdx.x * 256 + threadIdx.x;
  if (i > n) return;
  if (i == n) { mapping[n] = -1; return; }
  unsigned Kth = state[0];
  unsigned kneed = state[1];
  unsigned u = f2key(score[i]);
  int m = -1;
  if (u > Kth) {
    unsigned p = atomicAdd(&state[2], 1u);
    perm[p] = i;
    m = (int)p;
  } else if (u == Kth) {
    unsigned tt = atomicAdd(&state[3], 1u);
    if (tt < kneed) {
      unsigned p = atomicAdd(&state[2], 1u);
      perm[p] = i;
      m = (int)p;
    }
  }
  mapping[i] = m;
}

__global__ __launch_bounds__(256) void k_gather(const float* __restrict__ x,
                                                const int* __restrict__ perm,
                                                const float* __restrict__ score,
                                                const float* __restrict__ pw,
                                                float* __restrict__ out, int k) {
  int lane = threadIdx.x & 63;
  int node = blockIdx.x * 4 + (threadIdx.x >> 6);
  float4 w4 = *(const float4*)&pw[lane * 4];
  float nn = w4.x * w4.x + w4.y * w4.y + w4.z * w4.z + w4.w * w4.w;
#pragma unroll
  for (int o = 32; o > 0; o >>= 1) nn += __shfl_down(nn, o);
  nn = __shfl(nn, 0);
  if (node >= k) return;
  int i = perm[node];
  float tv = tanhf(score[i] / sqrtf(nn));
  float4 v = *(const float4*)&x[(size_t)i * CH + lane * 4];
  v.x *= tv; v.y *= tv; v.z *= tv; v.w *= tv;
  *(float4*)&out[(size_t)node * CH + lane * 4] = v;
}

// ----------------------------- final layer -----------------------------------

__global__ __launch_bounds__(256) void k_cvtb16(const float* __restrict__ x,
                                                unsigned short* __restrict__ xb, int n) {
  int lane = threadIdx.x & 63;
  int node = blockIdx.x * 4 + (threadIdx.x >> 6);
  if (node >= n) return;
  float4 a = *(const float4*)&x[(size_t)node * CH + lane * 4];
  ushort4 o;
  o.x = f2b_rn(a.x); o.y = f2b_rn(a.y); o.z = f2b_rn(a.z); o.w = f2b_rn(a.w);
  *(ushort4*)&xb[(size_t)node * CH + lane * 4] = o;
}

// fused maxagg (packed u16 max) + dual GEMM 256->3 + tanh*0.5
__global__ __launch_bounds__(256) void k_final(const unsigned short* __restrict__ XB,
                                               const int* __restrict__ row,
                                               const int* __restrict__ col,
                                               const float* __restrict__ wl,
                                               const float* __restrict__ wr,
                                               const float* __restrict__ b,
                                               float* __restrict__ out, int n) {
  int lane = threadIdx.x & 63;
  int node = blockIdx.x * 4 + (threadIdx.x >> 6);
  if (node >= n) return;
  int e0 = row[node], e1 = row[node + 1];
  uint2 m0 = make_uint2(0u, 0u), m1 = m0, m2 = m0, m3 = m0;
  int e = e0;
  for (; e + 4 <= e1; e += 4) {
    int s0 = col[e], s1 = col[e + 1], s2 = col[e + 2], s3 = col[e + 3];
    uint2 v0 = *(const uint2*)&XB[(size_t)s0 * CH + lane * 4];
    uint2 v1 = *(const uint2*)&XB[(size_t)s1 * CH + lane * 4];
    uint2 v2 = *(const uint2*)&XB[(size_t)s2 * CH + lane * 4];
    uint2 v3 = *(const uint2*)&XB[(size_t)s3 * CH + lane * 4];
    m0.x = pkmax_u16(m0.x, v0.x); m0.y = pkmax_u16(m0.y, v0.y);
    m1.x = pkmax_u16(m1.x, v1.x); m1.y = pkmax_u16(m1.y, v1.y);
    m2.x = pkmax_u16(m2.x, v2.x); m2.y = pkmax_u16(m2.y, v2.y);
    m3.x = pkmax_u16(m3.x, v3.x); m3.y = pkmax_u16(m3.y, v3.y);
  }
  for (; e < e1; e++) {
    uint2 v = *(const uint2*)&XB[(size_t)col[e] * CH + lane * 4];
    m0.x = pkmax_u16(m0.x, v.x);
    m0.y = pkmax_u16(m0.y, v.y);
  }
  m0.x = pkmax_u16(pkmax_u16(m0.x, m1.x), pkmax_u16(m2.x, m3.x));
  m0.y = pkmax_u16(pkmax_u16(m0.y, m1.y), pkmax_u16(m2.y, m3.y));
  float av[4];
  av[0] = b2f((unsigned short)(m0.x & 0xFFFFu));
  av[1] = b2f((unsigned short)(m0.x >> 16));
  av[2] = b2f((unsigned short)(m0.y & 0xFFFFu));
  av[3] = b2f((unsigned short)(m0.y >> 16));
  ushort4 sv4 = *(const ushort4*)&XB[(size_t)node * CH + lane * 4];
  float wlv[12], wrv[12];
  *(float4*)&wlv[0] = ((const float4*)(wl + 12 * lane))[0];
  *(float4*)&wlv[4] = ((const float4*)(wl + 12 * lane))[1];
  *(float4*)&wlv[8] = ((const float4*)(wl + 12 * lane))[2];
  *(float4*)&wrv[0] = ((const float4*)(wr + 12 * lane))[0];
  *(float4*)&wrv[4] = ((const float4*)(wr + 12 * lane))[1];
  *(float4*)&wrv[8] = ((const float4*)(wr + 12 * lane))[2];
  float sv[4] = {b2f(sv4.x), b2f(sv4.y), b2f(sv4.z), b2f(sv4.w)};
  float p[3] = {0.f, 0.f, 0.f};
#pragma unroll
  for (int q = 0; q < 4; q++)
#pragma unroll
    for (int jj = 0; jj < 3; jj++)
      p[jj] += av[q] * wlv[q * 3 + jj] + sv[q] * wrv[q * 3 + jj];
#pragma unroll
  for (int jj = 0; jj < 3; jj++) {
#pragma unroll
    for (int o = 32; o > 0; o >>= 1) p[jj] += __shfl_down(p[jj], o);
  }
  if (lane == 0) {
#pragma unroll
    for (int jj = 0; jj < 3; jj++)
      out[(size_t)node * 3 + jj] = tanhf(p[jj] + b[jj]) * 0.5f;
  }
}

// ----------------------------- host ------------------------------------------

extern "C" void kernel_launch(void* const* d_in, const int* in_sizes, int n_in,
                              void* d_out, int out_size, void* d_ws, size_t ws_size,
                              hipStream_t stream) {
  (void)in_sizes; (void)n_in; (void)out_size; (void)ws_size;
  const float* xin = (const float*)d_in[0];
  const int* ei = (const int*)d_in[1];
  const int* src0 = ei;
  const int* dst0 = ei + E_NUM;
  const float* w0l = (const float*)d_in[2];
  const float* w0r = (const float*)d_in[3];
  const float* b0 = (const float*)d_in[4];
  const float* dwl = (const float*)d_in[5];
  const float* dwr = (const float*)d_in[6];
  const float* db = (const float*)d_in[7];
  const float* poolw = (const float*)d_in[8];
  const float* uwl = (const float*)d_in[9];
  const float* uwr = (const float*)d_in[10];
  const float* ub = (const float*)d_in[11];
  const float* uwlL = (const float*)d_in[12];
  const float* uwrL = (const float*)d_in[13];
  const float* ubL = (const float*)d_in[14];
  float* out = (float*)d_out;

  char* base = (char*)d_ws;
  size_t off = 0;
  auto alloc = [&](size_t bytes) -> void* {
    void* p = base + off;
    off = (off + bytes + 255) & ~(size_t)255;
    return p;
  };

  const int n0 = 50000, n1 = 25000, n2 = 12500, n3 = 6250;
  float* X0 = (float*)alloc((size_t)n0 * CH * 4);
  float* X1 = (float*)alloc((size_t)n1 * CH * 4);
  float* X2 = (float*)alloc((size_t)n2 * CH * 4);
  float* AGG = (float*)alloc((size_t)n1 * CH * 4);
  float* PD = (float*)alloc((size_t)n1 * CH * 4);
  unsigned short* XB = (unsigned short*)alloc((size_t)n0 * CH * 2);
  unsigned short* X1B = (unsigned short*)alloc((size_t)n1 * CH * 2);
  unsigned short* X2B = (unsigned short*)alloc((size_t)n2 * CH * 2);
  int* eA = (int*)alloc((size_t)2 * E_NUM * 4);
  int* col0 = (int*)alloc((size_t)E_NUM * 4);
  int* col1 = (int*)alloc((size_t)E_NUM * 4);
  int* col2 = (int*)alloc((size_t)E_NUM * 4);
  int* col3 = (int*)alloc((size_t)E_NUM * 4);
  int* row0 = (int*)alloc((size_t)(n0 + 1) * 4);
  int* row1 = (int*)alloc((size_t)(n1 + 1) * 4);
  int* row2 = (int*)alloc((size_t)(n2 + 1) * 4);
  int* row3 = (int*)alloc((size_t)(n3 + 1) * 4);
  int* map1 = (int*)alloc((size_t)(n0 + 1) * 4);
  int* map2 = (int*)alloc((size_t)(n1 + 1) * 4);
  int* map3 = (int*)alloc((size_t)(n2 + 1) * 4);
  int* perm1 = (int*)alloc((size_t)n1 * 4);
  int* perm2 = (int*)alloc((size_t)n2 * 4);
  int* perm3 = (int*)alloc((size_t)n3 * 4);
  float* score = (float*)alloc((size_t)n0 * 4);
  int* deg = (int*)alloc((size_t)n0 * 4);
  int* incl = (int*)alloc((size_t)n0 * 4);
  int* cursor = (int*)alloc((size_t)n0 * 4);
  int* bsum = (int*)alloc((size_t)256 * 4);
  unsigned* state = (unsigned*)alloc(1024);
  unsigned* hist = (unsigned*)alloc((size_t)6 * 65536 * 4);  // 3 levels x [h1|h2]
  const size_t WSZ = (size_t)2 * 256 * 256;
  unsigned short* Wt0l = (unsigned short*)alloc((size_t)2 * 32 * 256 * 2);
  unsigned short* Wt0r = (unsigned short*)alloc((size_t)2 * 32 * 256 * 2);
  unsigned short* Wtdl = (unsigned short*)alloc(3 * WSZ * 2);
  unsigned short* Wtdr = (unsigned short*)alloc(3 * WSZ * 2);
  unsigned short* Wtul = (unsigned short*)alloc(2 * WSZ * 2);
  unsigned short* Wtur = (unsigned short*)alloc(2 * WSZ * 2);

  const int EG = (E_NUM + 255) / 256;

  // one fused weight-prep launch + one hist-zero for all 3 levels
  hipMemsetAsync(hist, 0, (size_t)6 * 65536 * 4, stream);
  k_wprep_all<<<(671744 + 255) / 256, 256, 0, stream>>>(w0l, w0r, dwl, dwr, uwl, uwr,
                                                        Wt0l, Wt0r, Wtdl, Wtdr, Wtul,
                                                        Wtur);

  auto scanLevel = [&](int n, int* rowp) {
    int nb = (n + 255) / 256;
    k_scan_block<<<nb, 256, 0, stream>>>(deg, n, incl, bsum);
    k_scan_final<<<nb, 256, 0, stream>>>(deg, incl, bsum, n, rowp, cursor);
  };

  auto poolLevel = [&](const float* X, const float* pw, int n, int k, int* mapping,
                       int* permL, float* Pout, unsigned* histL) {
    k_resolve<<<1, 1024, 0, stream>>>(histL, state, 0, k);
    k_hist2<<<(n + 255) / 256, 256, 0, stream>>>(score, n, state, histL + 65536);
    k_resolve<<<1, 1024, 0, stream>>>(histL + 65536, state, 1, k);
    k_compact<<<(n + 1 + 255) / 256, 256, 0, stream>>>(score, n, state, permL, mapping);
    k_gather<<<(k + 3) / 4, 256, 0, stream>>>(X, permL, score, pw, Pout, k);
  };

  auto gemm = [&](const float* A1, const float* A2, const unsigned short* W1t,
                  const unsigned short* W2t, const float* bias, float* o, int M, int K,
                  int scatter, const int* prm, const float* scw, float* sc, int terms,
                  unsigned short* ob, unsigned* histL) {
    k_gemm_mfma<<<(M + 63) / 64, 256, 0, stream>>>(A1, A2, W1t, W2t, bias, o, M, K,
                                                   scatter, prm, scw, sc, histL, terms,
                                                   ob);
  };

  // ---------------- encoder ----------------
  hipMemsetAsync(deg, 0, (size_t)n0 * 4, stream);
  k_deg<<<EG, 256, 0, stream>>>(dst0, n0, deg);
  scanLevel(n0, row0);
  k_fill<<<EG, 256, 0, stream>>>(src0, dst0, n0, cursor, col0);
  k_aggmax32<<<(n0 + 7) / 8, 256, 0, stream>>>(xin, row0, col0, AGG, n0);
  gemm(AGG, xin, Wt0l, Wt0r, b0, X0, n0, 32, 0, nullptr, poolw + 0 * CH, score, 3,
       nullptr, hist + 0 * 131072);

  // pool 1 (50000 -> 25000)
  poolLevel(X0, poolw + 0 * CH, n0, n1, map1, perm1, PD, hist + 0 * 131072);
  hipMemsetAsync(deg, 0, (size_t)n1 * 4, stream);
  k_relabel_deg<<<EG, 256, 0, stream>>>(src0, dst0, map1, n1, eA, eA + E_NUM, deg);
  scanLevel(n1, row1);
  k_fill<<<EG, 256, 0, stream>>>(eA, eA + E_NUM, n1, cursor, col1);
  k_aggmax4<<<(n1 + 3) / 4, 256, 0, stream>>>(PD, row1, col1, AGG, n1);
  gemm(AGG, PD, Wtdl + 0 * WSZ, Wtdr + 0 * WSZ, db + 0 * CH, X1, n1, 256, 0, nullptr,
       poolw + 1 * CH, score, 3, nullptr, hist + 1 * 131072);

  // pool 2 (25000 -> 12500)
  poolLevel(X1, poolw + 1 * CH, n1, n2, map2, perm2, PD, hist + 1 * 131072);
  hipMemsetAsync(deg, 0, (size_t)n2 * 4, stream);
  k_relabel_deg<<<EG, 256, 0, stream>>>(eA, eA + E_NUM, map2, n2, eA, eA + E_NUM, deg);
  scanLevel(n2, row2);
  k_fill<<<EG, 256, 0, stream>>>(eA, eA + E_NUM, n2, cursor, col2);
  k_aggmax4<<<(n2 + 3) / 4, 256, 0, stream>>>(PD, row2, col2, AGG, n2);
  gemm(AGG, PD, Wtdl + 1 * WSZ, Wtdr + 1 * WSZ, db + 1 * CH, X2, n2, 256, 0, nullptr,
       poolw + 2 * CH, score, 3, nullptr, hist + 2 * 131072);

  // pool 3 (12500 -> 6250)
  poolLevel(X2, poolw + 2 * CH, n2, n3, map3, perm3, PD, hist + 2 * 131072);
  hipMemsetAsync(deg, 0, (size_t)n3 * 4, stream);
  k_relabel_deg<<<EG, 256, 0, stream>>>(eA, eA + E_NUM, map3, n3, eA, eA + E_NUM, deg);
  scanLevel(n3, row3);
  k_fill<<<EG, 256, 0, stream>>>(eA, eA + E_NUM, n3, cursor, col3);
  k_aggmax4<<<(n3 + 3) / 4, 256, 0, stream>>>(PD, row3, col3, AGG, n3);
  gemm(AGG, PD, Wtdl + 2 * WSZ, Wtdr + 2 * WSZ, db + 2 * CH, X2, n3, 256, 1, perm3,
       nullptr, nullptr, 2, nullptr, nullptr);

  // ---------------- decoder (bf16 gather tables) ----------------
  k_cvtb16<<<(n2 + 3) / 4, 256, 0, stream>>>(X2, X2B, n2);
  k_aggmax4_b16<<<(n2 + 3) / 4, 256, 0, stream>>>(X2B, row2, col2, AGG, n2);
  gemm(AGG, X2, Wtul + 0 * WSZ, Wtur + 0 * WSZ, ub + 0 * CH, X1, n2, 256, 1, perm2,
       nullptr, nullptr, 2, nullptr, nullptr);

  k_cvtb16<<<(n1 + 3) / 4, 256, 0, stream>>>(X1, X1B, n1);
  k_aggmax4_b16<<<(n1 + 3) / 4, 256, 0, stream>>>(X1B, row1, col1, AGG, n1);
  // dec1: convert encoder X0 first; scatter epilogue reads old f32 X0 rows and
  // writes bf16 sums directly into XB (bit-identical to f32-write + convert).
  k_cvtb16<<<(n0 + 3) / 4, 256, 0, stream>>>(X0, XB, n0);
  gemm(AGG, X1, Wtul + 1 * WSZ, Wtur + 1 * WSZ, ub + 1 * CH, X0, n1, 256, 1, perm1,
       nullptr, nullptr, 2, XB, nullptr);

  k_final<<<(n0 + 3) / 4, 256, 0, stream>>>(XB, row0, col0, uwlL, uwrL, ubL, out, n0);
}

// Round 15
// 813.660 us; speedup vs baseline: 1.0760x; 1.0073x over previous
//
#include <hip/hip_runtime.h>
#include <math.h>

#define E_NUM 800000
#define CH 256

typedef __attribute__((ext_vector_type(8))) short short8;
typedef __attribute__((ext_vector_type(4))) float float4v;

__device__ __forceinline__ unsigned f2key(float s) {
  unsigned b = __float_as_uint(s);
  return (b & 0x80000000u) ? ~b : (b | 0x80000000u);  // order-preserving
}

// packed 2x16-bit unsigned max; valid as bf16 max for NON-NEGATIVE values
__device__ __forceinline__ unsigned pkmax_u16(unsigned a, unsigned b) {
  unsigned d;
  asm("v_pk_max_u16 %0, %1, %2" : "=v"(d) : "v"(a), "v"(b));
  return d;
}

// ----------------------------- CSR build ------------------------------------
// All 800k-edge kernels process 4 edges/thread (phase-batched) -> 4 independent
// latency chains per lane instead of 1 (r14 PMC: VALUBusy 0.3%, pure stall).

#define EG4 ((E_NUM + 1023) / 1024)

__global__ __launch_bounds__(256) void k_deg(const int* __restrict__ dst, int n,
                                             int* __restrict__ deg) {
  int base = blockIdx.x * 1024 + threadIdx.x;
  int d[4];
#pragma unroll
  for (int j = 0; j < 4; j++) {
    int e = base + j * 256;
    d[j] = (e < E_NUM) ? dst[e] : n;
  }
#pragma unroll
  for (int j = 0; j < 4; j++)
    if (d[j] < n) atomicAdd(&deg[d[j]], 1);
}

__global__ __launch_bounds__(256) void k_scan_block(const int* __restrict__ deg, int n,
                                                    int* __restrict__ incl,
                                                    int* __restrict__ bsum) {
  __shared__ int s[256];
  int i = blockIdx.x * 256 + threadIdx.x;
  int v = (i < n) ? deg[i] : 0;
  s[threadIdx.x] = v;
  __syncthreads();
  for (int o = 1; o < 256; o <<= 1) {
    int t = (threadIdx.x >= o) ? s[threadIdx.x - o] : 0;
    __syncthreads();
    s[threadIdx.x] += t;
    __syncthreads();
  }
  if (i < n) incl[i] = s[threadIdx.x];
  if (threadIdx.x == 255) bsum[blockIdx.x] = s[255];
}

// fused: each block computes its own bsum prefix; last block writes row[n].
__global__ __launch_bounds__(256) void k_scan_final(const int* __restrict__ deg,
                                                    const int* __restrict__ incl,
                                                    const int* __restrict__ bsum, int n,
                                                    int* __restrict__ row,
                                                    int* __restrict__ cursor) {
  __shared__ int red[256];
  int tid = threadIdx.x;
  int partial = 0;
  for (int b = tid; b < (int)blockIdx.x; b += 256) partial += bsum[b];
  red[tid] = partial;
  __syncthreads();
  for (int o = 128; o > 0; o >>= 1) {
    if (tid < o) red[tid] += red[tid + o];
    __syncthreads();
  }
  int base = red[0];
  int i = blockIdx.x * 256 + tid;
  if (i < n) {
    int r = incl[i] - deg[i] + base;
    row[i] = r;
    cursor[i] = r;
  }
  if (blockIdx.x == gridDim.x - 1 && tid == 0) row[n] = base + bsum[blockIdx.x];
}

// dummy edges (dst==n) dropped by the d<n guard; 4 edges/thread
__global__ __launch_bounds__(256) void k_fill(const int* __restrict__ src,
                                              const int* __restrict__ dst, int n,
                                              int* __restrict__ cursor,
                                              int* __restrict__ col) {
  int base = blockIdx.x * 1024 + threadIdx.x;
  int d[4], s[4];
#pragma unroll
  for (int j = 0; j < 4; j++) {
    int e = base + j * 256;
    d[j] = (e < E_NUM) ? dst[e] : n;
    s[j] = (e < E_NUM) ? src[e] : 0;
  }
  int p[4];
#pragma unroll
  for (int j = 0; j < 4; j++)
    if (d[j] < n) p[j] = atomicAdd(&cursor[d[j]], 1);
#pragma unroll
  for (int j = 0; j < 4; j++)
    if (d[j] < n) col[p[j]] = s[j];
}

// relabel, non-compacting, fused deg; 4 edges/thread (8 gathers in flight)
__global__ __launch_bounds__(256) void k_relabel_deg(const int* __restrict__ srcIn,
                                                     const int* __restrict__ dstIn,
                                                     const int* __restrict__ mapping,
                                                     int kNew, int* __restrict__ srcOut,
                                                     int* __restrict__ dstOut,
                                                     int* __restrict__ deg) {
  int base = blockIdx.x * 1024 + threadIdx.x;
  int sv[4], dv[4];
  bool ok[4];
#pragma unroll
  for (int j = 0; j < 4; j++) {
    int e = base + j * 256;
    ok[j] = (e < E_NUM);
    sv[j] = ok[j] ? srcIn[e] : 0;
    dv[j] = ok[j] ? dstIn[e] : 0;
  }
  int ns[4], nd[4];
#pragma unroll
  for (int j = 0; j < 4; j++) {
    ns[j] = ok[j] ? mapping[sv[j]] : -1;
    nd[j] = ok[j] ? mapping[dv[j]] : -1;
  }
#pragma unroll
  for (int j = 0; j < 4; j++) {
    if (!ok[j]) continue;
    int e = base + j * 256;
    bool valid = (ns[j] >= 0 && nd[j] >= 0);
    srcOut[e] = valid ? ns[j] : 0;
    dstOut[e] = valid ? nd[j] : kNew;
    if (valid) atomicAdd(&deg[nd[j]], 1);
  }
}

// ----------------------------- max aggregation -------------------------------

__device__ __forceinline__ float4 fmax4(float4 a, float4 b) {
  return make_float4(fmaxf(a.x, b.x), fmaxf(a.y, b.y), fmaxf(a.z, b.z), fmaxf(a.w, b.w));
}

__global__ __launch_bounds__(256) void k_aggmax32(const float* __restrict__ x,
                                                  const int* __restrict__ row,
                                                  const int* __restrict__ col,
                                                  float* __restrict__ out, int n) {
  int node = blockIdx.x * 8 + threadIdx.x / 32;
  int c = threadIdx.x % 32;
  if (node >= n) return;
  int e0 = row[node], e1 = row[node + 1];
  float m0 = -INFINITY, m1 = -INFINITY, m2 = -INFINITY, m3 = -INFINITY;
  int e = e0;
  for (; e + 4 <= e1; e += 4) {
    int s0 = col[e], s1 = col[e + 1], s2 = col[e + 2], s3 = col[e + 3];
    float v0 = x[(size_t)s0 * 32 + c];
    float v1 = x[(size_t)s1 * 32 + c];
    float v2 = x[(size_t)s2 * 32 + c];
    float v3 = x[(size_t)s3 * 32 + c];
    m0 = fmaxf(m0, v0); m1 = fmaxf(m1, v1); m2 = fmaxf(m2, v2); m3 = fmaxf(m3, v3);
  }
  for (; e < e1; e++) m0 = fmaxf(m0, x[(size_t)col[e] * 32 + c]);
  float m = fmaxf(fmaxf(m0, m1), fmaxf(m2, m3));
  out[(size_t)node * 32 + c] = (e1 > e0) ? m : 0.0f;
}

__global__ __launch_bounds__(256) void k_aggmax4(const float* __restrict__ x,
                                                 const int* __restrict__ row,
                                                 const int* __restrict__ col,
                                                 float* __restrict__ out, int n) {
  int lane = threadIdx.x & 63;
  int node = blockIdx.x * 4 + (threadIdx.x >> 6);
  if (node >= n) return;
  int e0 = row[node], e1 = row[node + 1];
  float4 m0 = make_float4(-INFINITY, -INFINITY, -INFINITY, -INFINITY);
  float4 m1 = m0, m2 = m0, m3 = m0;
  int e = e0;
  for (; e + 4 <= e1; e += 4) {
    int s0 = col[e], s1 = col[e + 1], s2 = col[e + 2], s3 = col[e + 3];
    float4 v0 = *(const float4*)&x[(size_t)s0 * CH + lane * 4];
    float4 v1 = *(const float4*)&x[(size_t)s1 * CH + lane * 4];
    float4 v2 = *(const float4*)&x[(size_t)s2 * CH + lane * 4];
    float4 v3 = *(const float4*)&x[(size_t)s3 * CH + lane * 4];
    m0 = fmax4(m0, v0); m1 = fmax4(m1, v1); m2 = fmax4(m2, v2); m3 = fmax4(m3, v3);
  }
  for (; e < e1; e++)
    m0 = fmax4(m0, *(const float4*)&x[(size_t)col[e] * CH + lane * 4]);
  float4 m = fmax4(fmax4(m0, m1), fmax4(m2, m3));
  if (e1 <= e0) m = make_float4(0.f, 0.f, 0.f, 0.f);
  *(float4*)&out[(size_t)node * CH + lane * 4] = m;
}

__device__ __forceinline__ float b2f(unsigned short s) {
  return __uint_as_float(((unsigned)s) << 16);
}

// bf16 table aggmax via packed u16 max (values are non-negative post-ReLU sums)
__global__ __launch_bounds__(256) void k_aggmax4_b16(const unsigned short* __restrict__ xb,
                                                     const int* __restrict__ row,
                                                     const int* __restrict__ col,
                                                     float* __restrict__ out, int n) {
  int lane = threadIdx.x & 63;
  int node = blockIdx.x * 4 + (threadIdx.x >> 6);
  if (node >= n) return;
  int e0 = row[node], e1 = row[node + 1];
  uint2 m0 = make_uint2(0u, 0u), m1 = m0, m2 = m0, m3 = m0;
  int e = e0;
  for (; e + 4 <= e1; e += 4) {
    int s0 = col[e], s1 = col[e + 1], s2 = col[e + 2], s3 = col[e + 3];
    uint2 v0 = *(const uint2*)&xb[(size_t)s0 * CH + lane * 4];
    uint2 v1 = *(const uint2*)&xb[(size_t)s1 * CH + lane * 4];
    uint2 v2 = *(const uint2*)&xb[(size_t)s2 * CH + lane * 4];
    uint2 v3 = *(const uint2*)&xb[(size_t)s3 * CH + lane * 4];
    m0.x = pkmax_u16(m0.x, v0.x); m0.y = pkmax_u16(m0.y, v0.y);
    m1.x = pkmax_u16(m1.x, v1.x); m1.y = pkmax_u16(m1.y, v1.y);
    m2.x = pkmax_u16(m2.x, v2.x); m2.y = pkmax_u16(m2.y, v2.y);
    m3.x = pkmax_u16(m3.x, v3.x); m3.y = pkmax_u16(m3.y, v3.y);
  }
  for (; e < e1; e++) {
    uint2 v = *(const uint2*)&xb[(size_t)col[e] * CH + lane * 4];
    m0.x = pkmax_u16(m0.x, v.x);
    m0.y = pkmax_u16(m0.y, v.y);
  }
  m0.x = pkmax_u16(pkmax_u16(m0.x, m1.x), pkmax_u16(m2.x, m3.x));
  m0.y = pkmax_u16(pkmax_u16(m0.y, m1.y), pkmax_u16(m2.y, m3.y));
  float4 m;
  m.x = b2f((unsigned short)(m0.x & 0xFFFFu));
  m.y = b2f((unsigned short)(m0.x >> 16));
  m.z = b2f((unsigned short)(m0.y & 0xFFFFu));
  m.w = b2f((unsigned short)(m0.y >> 16));
  *(float4*)&out[(size_t)node * CH + lane * 4] = m;
}

// ----------------------------- weight prep (fused, 1 launch) ------------------

__global__ __launch_bounds__(256) void k_wprep_all(
    const float* __restrict__ w0l, const float* __restrict__ w0r,
    const float* __restrict__ dwl, const float* __restrict__ dwr,
    const float* __restrict__ uwl, const float* __restrict__ uwr,
    unsigned short* __restrict__ Wt0l, unsigned short* __restrict__ Wt0r,
    unsigned short* __restrict__ Wtdl, unsigned short* __restrict__ Wtdr,
    unsigned short* __restrict__ Wtul, unsigned short* __restrict__ Wtur) {
  int idx = blockIdx.x * 256 + threadIdx.x;
  const float* src;
  unsigned short* dst;
  int K, rel;
  if (idx < 8192) { src = w0l; dst = Wt0l; K = 32; rel = idx; }
  else if (idx < 16384) { src = w0r; dst = Wt0r; K = 32; rel = idx - 8192; }
  else if (idx < 212992) { src = dwl; dst = Wtdl; K = 256; rel = idx - 16384; }
  else if (idx < 409600) { src = dwr; dst = Wtdr; K = 256; rel = idx - 212992; }
  else if (idx < 540672) { src = uwl; dst = Wtul; K = 256; rel = idx - 409600; }
  else if (idx < 671744) { src = uwr; dst = Wtur; K = 256; rel = idx - 540672; }
  else return;
  int n = rel % 256;
  int k = (rel / 256) % K;
  int m = rel / (256 * K);
  float v = src[rel];
  unsigned u = __float_as_uint(v);
  unsigned h = u & 0xFFFF0000u;
  float r = v - __uint_as_float(h);
  unsigned short hs = (unsigned short)(h >> 16);
  unsigned short ls = (unsigned short)(__float_as_uint(r) >> 16);
  int ib = k >> 5, kk = k & 31;
  size_t base = (size_t)m * 2 * K * 256;
  size_t o = ((size_t)ib * 256 + n) * 32 + kk;
  dst[base + o] = hs;
  dst[base + (size_t)K * 256 + o] = ls;
}

__device__ __forceinline__ unsigned short f2b_rn(float f) {
  unsigned u = __float_as_uint(f);
  u += 0x7FFFu + ((u >> 16) & 1u);
  return (unsigned short)(u >> 16);
}

// ----------------------------- MFMA dual GEMM --------------------------------

#define KSTR 40

__global__ __launch_bounds__(256) void k_gemm_mfma(
    const float* __restrict__ A1, const float* __restrict__ A2,
    const unsigned short* __restrict__ W1t, const unsigned short* __restrict__ W2t,
    const float* __restrict__ bias, float* __restrict__ out, int M, int K, int scatter,
    const int* __restrict__ perm, const float* __restrict__ scw,
    float* __restrict__ score, unsigned* __restrict__ hist1, int terms,
    unsigned short* __restrict__ outb) {
  __shared__ unsigned short As_h[64 * KSTR], As_l[64 * KSTR];
  __shared__ float sred[4][64];
  const int t = threadIdx.x;
  const int wave = t >> 6, lane = t & 63;
  const int l15 = lane & 15, qd = lane >> 4;
  const int bm0 = blockIdx.x * 64;
  float4v acc[4][4];
#pragma unroll
  for (int a = 0; a < 4; a++)
#pragma unroll
    for (int b = 0; b < 4; b++) acc[a][b] = (float4v)0.f;
  const int sa_m = t >> 2;
  const int sa_kc = (t & 3) * 8;
  const int rok = (bm0 + sa_m) < M;
  const int nIb = K >> 5;
  for (int ib = 0; ib < 2 * nIb; ib++) {
    const float* A = (ib < nIb) ? A1 : A2;
    const unsigned short* Wt = (ib < nIb) ? W1t : W2t;
    int ib0 = (ib < nIb) ? ib : ib - nIb;
    float va[8];
    {
      const float* ap = &A[(size_t)(bm0 + sa_m) * K + (ib0 << 5) + sa_kc];
      float4 v0 = rok ? *(const float4*)ap : make_float4(0, 0, 0, 0);
      float4 v1 = rok ? *(const float4*)(ap + 4) : make_float4(0, 0, 0, 0);
      va[0] = v0.x; va[1] = v0.y; va[2] = v0.z; va[3] = v0.w;
      va[4] = v1.x; va[5] = v1.y; va[6] = v1.z; va[7] = v1.w;
    }
    short8 bh[4], bl[4];
#pragma unroll
    for (int nt = 0; nt < 4; nt++) {
      size_t rowb = ((size_t)ib0 * 256 + wave * 64 + nt * 16 + l15) * 32 + qd * 8;
      bh[nt] = *(const short8*)&Wt[rowb];
      bl[nt] = *(const short8*)&Wt[(size_t)K * 256 + rowb];
    }
    unsigned hp[4], lp[4];
#pragma unroll
    for (int e = 0; e < 4; e++) {
      unsigned u0 = __float_as_uint(va[2 * e]);
      unsigned u1 = __float_as_uint(va[2 * e + 1]);
      unsigned h0 = u0 & 0xFFFF0000u, h1 = u1 & 0xFFFF0000u;
      float r0 = va[2 * e] - __uint_as_float(h0);
      float r1 = va[2 * e + 1] - __uint_as_float(h1);
      hp[e] = (h0 >> 16) | h1;
      lp[e] = (__float_as_uint(r0) >> 16) | (__float_as_uint(r1) & 0xFFFF0000u);
    }
    __syncthreads();
    *(uint4*)&As_h[sa_m * KSTR + sa_kc] = make_uint4(hp[0], hp[1], hp[2], hp[3]);
    if (terms == 3)
      *(uint4*)&As_l[sa_m * KSTR + sa_kc] = make_uint4(lp[0], lp[1], lp[2], lp[3]);
    __syncthreads();
    short8 ah[4], al[4];
#pragma unroll
    for (int mt = 0; mt < 4; mt++) {
      int r = (mt * 16 + l15) * KSTR + qd * 8;
      ah[mt] = *(const short8*)&As_h[r];
      if (terms == 3) al[mt] = *(const short8*)&As_l[r];
    }
#pragma unroll
    for (int mt = 0; mt < 4; mt++)
#pragma unroll
      for (int nt = 0; nt < 4; nt++) {
        acc[mt][nt] =
            __builtin_amdgcn_mfma_f32_16x16x32_bf16(bh[nt], ah[mt], acc[mt][nt], 0, 0, 0);
        acc[mt][nt] =
            __builtin_amdgcn_mfma_f32_16x16x32_bf16(bl[nt], ah[mt], acc[mt][nt], 0, 0, 0);
        if (terms == 3)
          acc[mt][nt] = __builtin_amdgcn_mfma_f32_16x16x32_bf16(bh[nt], al[mt],
                                                                acc[mt][nt], 0, 0, 0);
      }
  }
  const int col0 = wave * 64;
  if (scw) {
    if (t < 64) { sred[0][t] = 0.f; sred[1][t] = 0.f; sred[2][t] = 0.f; sred[3][t] = 0.f; }
    __syncthreads();
  }
  float bias4[4][4], scw4[4][4];
#pragma unroll
  for (int nt = 0; nt < 4; nt++) {
    int cb = col0 + nt * 16 + qd * 4;
    *(float4*)bias4[nt] = *(const float4*)&bias[cb];
    if (scw) *(float4*)scw4[nt] = *(const float4*)&scw[cb];
  }
#pragma unroll
  for (int mt = 0; mt < 4; mt++) {
    int p = bm0 + mt * 16 + l15;
    float sp = 0.f;
    if (p < M) {
      if (scatter) {
        size_t rb = (size_t)perm[p] * CH + col0 + qd * 4;
#pragma unroll
        for (int nt = 0; nt < 4; nt++) {
          float4 old = *(const float4*)&out[rb + nt * 16];
          float4 v;
          v.x = old.x + fmaxf(acc[mt][nt][0] + bias4[nt][0], 0.f);
          v.y = old.y + fmaxf(acc[mt][nt][1] + bias4[nt][1], 0.f);
          v.z = old.z + fmaxf(acc[mt][nt][2] + bias4[nt][2], 0.f);
          v.w = old.w + fmaxf(acc[mt][nt][3] + bias4[nt][3], 0.f);
          if (outb) {
            ushort4 o;
            o.x = f2b_rn(v.x); o.y = f2b_rn(v.y); o.z = f2b_rn(v.z); o.w = f2b_rn(v.w);
            *(ushort4*)&outb[rb + nt * 16] = o;
          } else {
            *(float4*)&out[rb + nt * 16] = v;
          }
        }
      } else {
        size_t rb = (size_t)p * CH + col0 + qd * 4;
#pragma unroll
        for (int nt = 0; nt < 4; nt++) {
          float4 v;
          v.x = fmaxf(acc[mt][nt][0] + bias4[nt][0], 0.f);
          v.y = fmaxf(acc[mt][nt][1] + bias4[nt][1], 0.f);
          v.z = fmaxf(acc[mt][nt][2] + bias4[nt][2], 0.f);
          v.w = fmaxf(acc[mt][nt][3] + bias4[nt][3], 0.f);
          *(float4*)&out[rb + nt * 16] = v;
          if (scw)
            sp += v.x * scw4[nt][0] + v.y * scw4[nt][1] + v.z * scw4[nt][2] +
                  v.w * scw4[nt][3];
        }
      }
    }
    if (scw) {
      sp += __shfl_xor(sp, 16);
      sp += __shfl_xor(sp, 32);
      if (qd == 0) sred[wave][mt * 16 + l15] = sp;
    }
  }
  if (scw) {
    __syncthreads();
    if (t < 64 && bm0 + t < M) {
      float s = sred[0][t] + sred[1][t] + sred[2][t] + sred[3][t];
      score[bm0 + t] = s;
      atomicAdd(&hist1[f2key(s) >> 16], 1u);
    }
  }
}

// ----------------------------- distributed top-k select ----------------------
// state: [0]=Kth key [1]=kneed ties [2]=cnt_keep [3]=cnt_eq [4]=prefix16 [5]=kneed2

__global__ __launch_bounds__(1024) void k_resolve(const unsigned* __restrict__ hist,
                                                  unsigned* __restrict__ state, int pass,
                                                  int k0) {
  __shared__ unsigned csum[1024];
  int t = threadIdx.x;
  int base = 65535 - 64 * t;
  unsigned s = 0;
  for (int j = 0; j < 64; j++) s += hist[base - j];
  csum[t] = s;
  __syncthreads();
  for (int o = 1; o < 1024; o <<= 1) {
    unsigned v = (t >= o) ? csum[t - o] : 0u;
    __syncthreads();
    csum[t] += v;
    __syncthreads();
  }
  unsigned cumBefore = csum[t] - s;
  unsigned kneed = (pass == 0) ? (unsigned)k0 : state[5];
  if (cumBefore < kneed && kneed <= cumBefore + s) {
    unsigned cum = cumBefore;
    for (int j = 0; j < 64; j++) {
      unsigned c = hist[base - j];
      if (cum + c >= kneed) {
        unsigned bucket = (unsigned)(base - j);
        if (pass == 0) {
          state[4] = bucket;
          state[5] = kneed - cum;
        } else {
          state[0] = (state[4] << 16) | bucket;
          state[1] = kneed - cum;
          state[2] = 0u;
          state[3] = 0u;
        }
        break;
      }
      cum += c;
    }
  }
}

__global__ __launch_bounds__(256) void k_hist2(const float* __restrict__ score, int n,
                                               const unsigned* __restrict__ state,
                                               unsigned* __restrict__ hist2) {
  int i = blockIdx.x * 256 + threadIdx.x;
  if (i >= n) return;
  unsigned u = f2key(score[i]);
  if ((u >> 16) == state[4]) atomicAdd(&hist2[u & 0xFFFFu], 1u);
}

__global__ __launch_bounds__(256) void k_compact(const float* __restrict__ score, int n,
                                                 unsigned* __restrict__ state,
                                                 int* __restrict__ perm,
                                                 int* __restrict__ mapping) {
  int i = blockIdx.x * 256 + threadIdx.x;
  if (i > n) return;
  if (i == n) { mapping[n] = -1; return; }
  unsigned Kth = state[0];
  unsigned kneed = state[1];
  unsigned u = f2key(score[i]);
  int m = -1;
  if (u > Kth) {
    unsigned p = atomicAdd(&state[2], 1u);
    perm[p] = i;
    m = (int)p;
  } else if (u == Kth) {
    unsigned tt = atomicAdd(&state[3], 1u);
    if (tt < kneed) {
      unsigned p = atomicAdd(&state[2], 1u);
      perm[p] = i;
      m = (int)p;
    }
  }
  mapping[i] = m;
}

__global__ __launch_bounds__(256) void k_gather(const float* __restrict__ x,
                                                const int* __restrict__ perm,
                                                const float* __restrict__ score,
                                                const float* __restrict__ pw,
                                                float* __restrict__ out, int k) {
  int lane = threadIdx.x & 63;
  int node = blockIdx.x * 4 + (threadIdx.x >> 6);
  float4 w4 = *(const float4*)&pw[lane * 4];
  float nn = w4.x * w4.x + w4.y * w4.y + w4.z * w4.z + w4.w * w4.w;
#pragma unroll
  for (int o = 32; o > 0; o >>= 1) nn += __shfl_down(nn, o);
  nn = __shfl(nn, 0);
  if (node >= k) return;
  int i = perm[node];
  float tv = tanhf(score[i] / sqrtf(nn));
  float4 v = *(const float4*)&x[(size_t)i * CH + lane * 4];
  v.x *= tv; v.y *= tv; v.z *= tv; v.w *= tv;
  *(float4*)&out[(size_t)node * CH + lane * 4] = v;
}

// ----------------------------- final layer -----------------------------------

__global__ __launch_bounds__(256) void k_cvtb16(const float* __restrict__ x,
                                                unsigned short* __restrict__ xb, int n) {
  int lane = threadIdx.x & 63;
  int node = blockIdx.x * 4 + (threadIdx.x >> 6);
  if (node >= n) return;
  float4 a = *(const float4*)&x[(size_t)node * CH + lane * 4];
  ushort4 o;
  o.x = f2b_rn(a.x); o.y = f2b_rn(a.y); o.z = f2b_rn(a.z); o.w = f2b_rn(a.w);
  *(ushort4*)&xb[(size_t)node * CH + lane * 4] = o;
}

// fused maxagg (packed u16 max) + dual GEMM 256->3 + tanh*0.5
__global__ __launch_bounds__(256) void k_final(const unsigned short* __restrict__ XB,
                                               const int* __restrict__ row,
                                               const int* __restrict__ col,
                                               const float* __restrict__ wl,
                                               const float* __restrict__ wr,
                                               const float* __restrict__ b,
                                               float* __restrict__ out, int n) {
  int lane = threadIdx.x & 63;
  int node = blockIdx.x * 4 + (threadIdx.x >> 6);
  if (node >= n) return;
  int e0 = row[node], e1 = row[node + 1];
  uint2 m0 = make_uint2(0u, 0u), m1 = m0, m2 = m0, m3 = m0;
  int e = e0;
  for (; e + 4 <= e1; e += 4) {
    int s0 = col[e], s1 = col[e + 1], s2 = col[e + 2], s3 = col[e + 3];
    uint2 v0 = *(const uint2*)&XB[(size_t)s0 * CH + lane * 4];
    uint2 v1 = *(const uint2*)&XB[(size_t)s1 * CH + lane * 4];
    uint2 v2 = *(const uint2*)&XB[(size_t)s2 * CH + lane * 4];
    uint2 v3 = *(const uint2*)&XB[(size_t)s3 * CH + lane * 4];
    m0.x = pkmax_u16(m0.x, v0.x); m0.y = pkmax_u16(m0.y, v0.y);
    m1.x = pkmax_u16(m1.x, v1.x); m1.y = pkmax_u16(m1.y, v1.y);
    m2.x = pkmax_u16(m2.x, v2.x); m2.y = pkmax_u16(m2.y, v2.y);
    m3.x = pkmax_u16(m3.x, v3.x); m3.y = pkmax_u16(m3.y, v3.y);
  }
  for (; e < e1; e++) {
    uint2 v = *(const uint2*)&XB[(size_t)col[e] * CH + lane * 4];
    m0.x = pkmax_u16(m0.x, v.x);
    m0.y = pkmax_u16(m0.y, v.y);
  }
  m0.x = pkmax_u16(pkmax_u16(m0.x, m1.x), pkmax_u16(m2.x, m3.x));
  m0.y = pkmax_u16(pkmax_u16(m0.y, m1.y), pkmax_u16(m2.y, m3.y));
  float av[4];
  av[0] = b2f((unsigned short)(m0.x & 0xFFFFu));
  av[1] = b2f((unsigned short)(m0.x >> 16));
  av[2] = b2f((unsigned short)(m0.y & 0xFFFFu));
  av[3] = b2f((unsigned short)(m0.y >> 16));
  ushort4 sv4 = *(const ushort4*)&XB[(size_t)node * CH + lane * 4];
  float wlv[12], wrv[12];
  *(float4*)&wlv[0] = ((const float4*)(wl + 12 * lane))[0];
  *(float4*)&wlv[4] = ((const float4*)(wl + 12 * lane))[1];
  *(float4*)&wlv[8] = ((const float4*)(wl + 12 * lane))[2];
  *(float4*)&wrv[0] = ((const float4*)(wr + 12 * lane))[0];
  *(float4*)&wrv[4] = ((const float4*)(wr + 12 * lane))[1];
  *(float4*)&wrv[8] = ((const float4*)(wr + 12 * lane))[2];
  float sv[4] = {b2f(sv4.x), b2f(sv4.y), b2f(sv4.z), b2f(sv4.w)};
  float p[3] = {0.f, 0.f, 0.f};
#pragma unroll
  for (int q = 0; q < 4; q++)
#pragma unroll
    for (int jj = 0; jj < 3; jj++)
      p[jj] += av[q] * wlv[q * 3 + jj] + sv[q] * wrv[q * 3 + jj];
#pragma unroll
  for (int jj = 0; jj < 3; jj++) {
#pragma unroll
    for (int o = 32; o > 0; o >>= 1) p[jj] += __shfl_down(p[jj], o);
  }
  if (lane == 0) {
#pragma unroll
    for (int jj = 0; jj < 3; jj++)
      out[(size_t)node * 3 + jj] = tanhf(p[jj] + b[jj]) * 0.5f;
  }
}

// ----------------------------- host ------------------------------------------

extern "C" void kernel_launch(void* const* d_in, const int* in_sizes, int n_in,
                              void* d_out, int out_size, void* d_ws, size_t ws_size,
                              hipStream_t stream) {
  (void)in_sizes; (void)n_in; (void)out_size; (void)ws_size;
  const float* xin = (const float*)d_in[0];
  const int* ei = (const int*)d_in[1];
  const int* src0 = ei;
  const int* dst0 = ei + E_NUM;
  const float* w0l = (const float*)d_in[2];
  const float* w0r = (const float*)d_in[3];
  const float* b0 = (const float*)d_in[4];
  const float* dwl = (const float*)d_in[5];
  const float* dwr = (const float*)d_in[6];
  const float* db = (const float*)d_in[7];
  const float* poolw = (const float*)d_in[8];
  const float* uwl = (const float*)d_in[9];
  const float* uwr = (const float*)d_in[10];
  const float* ub = (const float*)d_in[11];
  const float* uwlL = (const float*)d_in[12];
  const float* uwrL = (const float*)d_in[13];
  const float* ubL = (const float*)d_in[14];
  float* out = (float*)d_out;

  char* base = (char*)d_ws;
  size_t off = 0;
  auto alloc = [&](size_t bytes) -> void* {
    void* p = base + off;
    off = (off + bytes + 255) & ~(size_t)255;
    return p;
  };

  const int n0 = 50000, n1 = 25000, n2 = 12500, n3 = 6250;
  float* X0 = (float*)alloc((size_t)n0 * CH * 4);
  float* X1 = (float*)alloc((size_t)n1 * CH * 4);
  float* X2 = (float*)alloc((size_t)n2 * CH * 4);
  float* AGG = (float*)alloc((size_t)n1 * CH * 4);
  float* PD = (float*)alloc((size_t)n1 * CH * 4);
  unsigned short* XB = (unsigned short*)alloc((size_t)n0 * CH * 2);
  unsigned short* X1B = (unsigned short*)alloc((size_t)n1 * CH * 2);
  unsigned short* X2B = (unsigned short*)alloc((size_t)n2 * CH * 2);
  int* eA = (int*)alloc((size_t)2 * E_NUM * 4);
  int* col0 = (int*)alloc((size_t)E_NUM * 4);
  int* col1 = (int*)alloc((size_t)E_NUM * 4);
  int* col2 = (int*)alloc((size_t)E_NUM * 4);
  int* col3 = (int*)alloc((size_t)E_NUM * 4);
  int* row0 = (int*)alloc((size_t)(n0 + 1) * 4);
  int* row1 = (int*)alloc((size_t)(n1 + 1) * 4);
  int* row2 = (int*)alloc((size_t)(n2 + 1) * 4);
  int* row3 = (int*)alloc((size_t)(n3 + 1) * 4);
  int* map1 = (int*)alloc((size_t)(n0 + 1) * 4);
  int* map2 = (int*)alloc((size_t)(n1 + 1) * 4);
  int* map3 = (int*)alloc((size_t)(n2 + 1) * 4);
  int* perm1 = (int*)alloc((size_t)n1 * 4);
  int* perm2 = (int*)alloc((size_t)n2 * 4);
  int* perm3 = (int*)alloc((size_t)n3 * 4);
  float* score = (float*)alloc((size_t)n0 * 4);
  int* deg = (int*)alloc((size_t)n0 * 4);
  int* incl = (int*)alloc((size_t)n0 * 4);
  int* cursor = (int*)alloc((size_t)n0 * 4);
  int* bsum = (int*)alloc((size_t)256 * 4);
  unsigned* state = (unsigned*)alloc(1024);
  unsigned* hist = (unsigned*)alloc((size_t)6 * 65536 * 4);  // 3 levels x [h1|h2]
  const size_t WSZ = (size_t)2 * 256 * 256;
  unsigned short* Wt0l = (unsigned short*)alloc((size_t)2 * 32 * 256 * 2);
  unsigned short* Wt0r = (unsigned short*)alloc((size_t)2 * 32 * 256 * 2);
  unsigned short* Wtdl = (unsigned short*)alloc(3 * WSZ * 2);
  unsigned short* Wtdr = (unsigned short*)alloc(3 * WSZ * 2);
  unsigned short* Wtul = (unsigned short*)alloc(2 * WSZ * 2);
  unsigned short* Wtur = (unsigned short*)alloc(2 * WSZ * 2);

  // one fused weight-prep launch + one hist-zero for all 3 levels
  hipMemsetAsync(hist, 0, (size_t)6 * 65536 * 4, stream);
  k_wprep_all<<<(671744 + 255) / 256, 256, 0, stream>>>(w0l, w0r, dwl, dwr, uwl, uwr,
                                                        Wt0l, Wt0r, Wtdl, Wtdr, Wtul,
                                                        Wtur);

  auto scanLevel = [&](int n, int* rowp) {
    int nb = (n + 255) / 256;
    k_scan_block<<<nb, 256, 0, stream>>>(deg, n, incl, bsum);
    k_scan_final<<<nb, 256, 0, stream>>>(deg, incl, bsum, n, rowp, cursor);
  };

  auto poolLevel = [&](const float* X, const float* pw, int n, int k, int* mapping,
                       int* permL, float* Pout, unsigned* histL) {
    k_resolve<<<1, 1024, 0, stream>>>(histL, state, 0, k);
    k_hist2<<<(n + 255) / 256, 256, 0, stream>>>(score, n, state, histL + 65536);
    k_resolve<<<1, 1024, 0, stream>>>(histL + 65536, state, 1, k);
    k_compact<<<(n + 1 + 255) / 256, 256, 0, stream>>>(score, n, state, permL, mapping);
    k_gather<<<(k + 3) / 4, 256, 0, stream>>>(X, permL, score, pw, Pout, k);
  };

  auto gemm = [&](const float* A1, const float* A2, const unsigned short* W1t,
                  const unsigned short* W2t, const float* bias, float* o, int M, int K,
                  int scatter, const int* prm, const float* scw, float* sc, int terms,
                  unsigned short* ob, unsigned* histL) {
    k_gemm_mfma<<<(M + 63) / 64, 256, 0, stream>>>(A1, A2, W1t, W2t, bias, o, M, K,
                                                   scatter, prm, scw, sc, histL, terms,
                                                   ob);
  };

  // ---------------- encoder ----------------
  hipMemsetAsync(deg, 0, (size_t)n0 * 4, stream);
  k_deg<<<EG4, 256, 0, stream>>>(dst0, n0, deg);
  scanLevel(n0, row0);
  k_fill<<<EG4, 256, 0, stream>>>(src0, dst0, n0, cursor, col0);
  k_aggmax32<<<(n0 + 7) / 8, 256, 0, stream>>>(xin, row0, col0, AGG, n0);
  gemm(AGG, xin, Wt0l, Wt0r, b0, X0, n0, 32, 0, nullptr, poolw + 0 * CH, score, 3,
       nullptr, hist + 0 * 131072);

  // pool 1 (50000 -> 25000)
  poolLevel(X0, poolw + 0 * CH, n0, n1, map1, perm1, PD, hist + 0 * 131072);
  hipMemsetAsync(deg, 0, (size_t)n1 * 4, stream);
  k_relabel_deg<<<EG4, 256, 0, stream>>>(src0, dst0, map1, n1, eA, eA + E_NUM, deg);
  scanLevel(n1, row1);
  k_fill<<<EG4, 256, 0, stream>>>(eA, eA + E_NUM, n1, cursor, col1);
  k_aggmax4<<<(n1 + 3) / 4, 256, 0, stream>>>(PD, row1, col1, AGG, n1);
  gemm(AGG, PD, Wtdl + 0 * WSZ, Wtdr + 0 * WSZ, db + 0 * CH, X1, n1, 256, 0, nullptr,
       poolw + 1 * CH, score, 3, nullptr, hist + 1 * 131072);

  // pool 2 (25000 -> 12500)
  poolLevel(X1, poolw + 1 * CH, n1, n2, map2, perm2, PD, hist + 1 * 131072);
  hipMemsetAsync(deg, 0, (size_t)n2 * 4, stream);
  k_relabel_deg<<<EG4, 256, 0, stream>>>(eA, eA + E_NUM, map2, n2, eA, eA + E_NUM, deg);
  scanLevel(n2, row2);
  k_fill<<<EG4, 256, 0, stream>>>(eA, eA + E_NUM, n2, cursor, col2);
  k_aggmax4<<<(n2 + 3) / 4, 256, 0, stream>>>(PD, row2, col2, AGG, n2);
  gemm(AGG, PD, Wtdl + 1 * WSZ, Wtdr + 1 * WSZ, db + 1 * CH, X2, n2, 256, 0, nullptr,
       poolw + 2 * CH, score, 3, nullptr, hist + 2 * 131072);

  // pool 3 (12500 -> 6250)
  poolLevel(X2, poolw + 2 * CH, n2, n3, map3, perm3, PD, hist + 2 * 131072);
  hipMemsetAsync(deg, 0, (size_t)n3 * 4, stream);
  k_relabel_deg<<<EG4, 256, 0, stream>>>(eA, eA + E_NUM, map3, n3, eA, eA + E_NUM, deg);
  scanLevel(n3, row3);
  k_fill<<<EG4, 256, 0, stream>>>(eA, eA + E_NUM, n3, cursor, col3);
  k_aggmax4<<<(n3 + 3) / 4, 256, 0, stream>>>(PD, row3, col3, AGG, n3);
  gemm(AGG, PD, Wtdl + 2 * WSZ, Wtdr + 2 * WSZ, db + 2 * CH, X2, n3, 256, 1, perm3,
       nullptr, nullptr, 2, nullptr, nullptr);

  // ---------------- decoder (bf16 gather tables) ----------------
  k_cvtb16<<<(n2 + 3) / 4, 256, 0, stream>>>(X2, X2B, n2);
  k_aggmax4_b16<<<(n2 + 3) / 4, 256, 0, stream>>>(X2B, row2, col2, AGG, n2);
  gemm(AGG, X2, Wtul + 0 * WSZ, Wtur + 0 * WSZ, ub + 0 * CH, X1, n2, 256, 1, perm2,
       nullptr, nullptr, 2, nullptr, nullptr);

  k_cvtb16<<<(n1 + 3) / 4, 256, 0, stream>>>(X1, X1B, n1);
  k_aggmax4_b16<<<(n1 + 3) / 4, 256, 0, stream>>>(X1B, row1, col1, AGG, n1);
  k_cvtb16<<<(n0 + 3) / 4, 256, 0, stream>>>(X0, XB, n0);
  gemm(AGG, X1, Wtul + 1 * WSZ, Wtur + 1 * WSZ, ub + 1 * CH, X0, n1, 256, 1, perm1,
       nullptr, nullptr, 2, XB, nullptr);

  k_final<<<(n0 + 3) / 4, 256, 0, stream>>>(XB, row0, col0, uwlL, uwrL, ubL, out, n0);
}